// Round 1
// baseline (1039.127 us; speedup 1.0000x reference)
//
#include <hip/hip_runtime.h>
#include <stdint.h>

#define Nn 256
#define Mm 512
#define Dd 256

typedef unsigned short u16;
typedef unsigned int u32;
typedef __attribute__((ext_vector_type(8))) short bf16x8;
typedef __attribute__((ext_vector_type(4))) float f32x4;

__device__ __forceinline__ u16 f2b(float f) {
    unsigned u = __float_as_uint(f);
    return (u16)((u + 0x7FFFu + ((u >> 16) & 1u)) >> 16);  // RNE to bf16
}
__device__ __forceinline__ float b2f(u16 h) {
    return __uint_as_float(((unsigned)h) << 16);
}
__device__ __forceinline__ void glds16(const u16* g, u16* l) {
    __builtin_amdgcn_global_load_lds((const __attribute__((address_space(1))) void*)g,
                                     (__attribute__((address_space(3))) void*)l, 16, 0, 0);
}

// ---------------------------------------------------------------------------
// Kernel 1a: partial column sums. grid = Nn*4; block (n, c) sums 128 rows.
// ---------------------------------------------------------------------------
__global__ __launch_bounds__(256) void mean_part_kernel(const float* __restrict__ x,
                                                        float* __restrict__ meanPart) {
    const int bid = blockIdx.x;
    const int n = bid >> 2, c = bid & 3;
    const int tid = threadIdx.x;
    const float* xb = x + (size_t)n * Mm * Dd + (size_t)c * 128 * Dd;
    float a0 = 0.f, a1 = 0.f, a2 = 0.f, a3 = 0.f;
    for (int m = 0; m < 128; m += 4) {
        a0 += xb[(m + 0) * Dd + tid];
        a1 += xb[(m + 1) * Dd + tid];
        a2 += xb[(m + 2) * Dd + tid];
        a3 += xb[(m + 3) * Dd + tid];
    }
    meanPart[((size_t)n * 4 + c) * Dd + tid] = a0 + a1 + a2 + a3;
}

// ---------------------------------------------------------------------------
// Kernel 1b: center + emit xn bf16 [n][m][d] and xnT bf16 [n][d][m].
// ---------------------------------------------------------------------------
__global__ __launch_bounds__(256) void center_tr_kernel(const float* __restrict__ x,
                                                        const float* __restrict__ meanPart,
                                                        u16* __restrict__ xn,
                                                        u16* __restrict__ xnT) {
    __shared__ float meanS[Dd];
    __shared__ u16 tileS[64 * 66];
    const int bid = blockIdx.x;
    const int n = bid >> 3, mt = bid & 7;
    const int tid = threadIdx.x;

    const float* mp = meanPart + (size_t)n * 4 * Dd;
    meanS[tid] = (mp[tid] + mp[Dd + tid] + mp[2 * Dd + tid] + mp[3 * Dd + tid]) * (1.0f / Mm);
    __syncthreads();

    const float* xb = x + (size_t)n * Mm * Dd;
    u16* xnb = xn + (size_t)n * Mm * Dd;
    u16* xtb = xnT + (size_t)n * Dd * Mm;
    const int mrow = tid >> 4, dq = tid & 15;      // phase A
    const int tx2 = (tid & 31) * 2, ty = tid >> 5; // phase B

    for (int dt = 0; dt < Dd / 64; ++dt) {
        #pragma unroll
        for (int rr = 0; rr < 4; ++rr) {
            int ml = mrow + 16 * rr;
            int m = mt * 64 + ml;
            int d = dt * 64 + dq * 4;
            float4 v = *(const float4*)(xb + (size_t)m * Dd + d);
            float4 mu = *(const float4*)(meanS + d);
            u16 b0 = f2b(v.x - mu.x), b1 = f2b(v.y - mu.y);
            u16 b2 = f2b(v.z - mu.z), b3 = f2b(v.w - mu.w);
            u32 lo = (u32)b0 | ((u32)b1 << 16);
            u32 hi = (u32)b2 | ((u32)b3 << 16);
            *(uint2*)(xnb + (size_t)m * Dd + d) = make_uint2(lo, hi);
            tileS[(dq * 4 + 0) * 66 + ml] = b0;
            tileS[(dq * 4 + 1) * 66 + ml] = b1;
            tileS[(dq * 4 + 2) * 66 + ml] = b2;
            tileS[(dq * 4 + 3) * 66 + ml] = b3;
        }
        __syncthreads();
        #pragma unroll
        for (int r = 0; r < 8; ++r) {
            int dl = r * 8 + ty;
            u32 w = *(const u32*)(tileS + dl * 66 + tx2);
            *(u32*)(xtb + (size_t)(dt * 64 + dl) * Mm + mt * 64 + tx2) = w;
        }
        __syncthreads();
    }
}

// ---------------------------------------------------------------------------
// Kernel 2: sigma[n] = XnT @ XnT^T (raw fp32). XCD-swizzled.
// ---------------------------------------------------------------------------
__global__ __launch_bounds__(256) void sigma_kernel(const u16* __restrict__ xnT,
                                                    float* __restrict__ sigma) {
    __shared__ u16 sA[128 * 32];
    __shared__ u16 sB[128 * 32];
    const int bid = blockIdx.x;
    const int xcd = bid & 7, slot = bid >> 3;
    const int t = slot & 3;
    const int n = ((slot >> 2) << 3) | xcd;
    const int tr = t >> 1, tc = t & 1;
    const int tid = threadIdx.x;
    const int lane = tid & 63, wave = tid >> 6;
    const int wr = wave >> 1, wc = wave & 1;
    const int l15 = lane & 15, quad = lane >> 4;
    const int row0 = tid >> 2, q = tid & 3;
    const int wb8 = (tid & 192) * 8;

    const u16* base = xnT + (size_t)n * Dd * Mm;
    const u16* gA = base + (size_t)(tr * 128) * Mm;
    const u16* gB = base + (size_t)(tc * 128) * Mm;

    f32x4 acc[4][4];
    #pragma unroll
    for (int i = 0; i < 4; ++i)
        #pragma unroll
        for (int j = 0; j < 4; ++j) acc[i][j] = (f32x4){0.f, 0.f, 0.f, 0.f};

    for (int kk = 0; kk < Mm; kk += 32) {
        glds16(gA + (size_t)row0 * Mm + kk + q * 8, sA + wb8);
        glds16(gA + (size_t)(row0 + 64) * Mm + kk + q * 8, sA + 2048 + wb8);
        glds16(gB + (size_t)row0 * Mm + kk + q * 8, sB + wb8);
        glds16(gB + (size_t)(row0 + 64) * Mm + kk + q * 8, sB + 2048 + wb8);
        __syncthreads();
        bf16x8 a[4], b[4];
        #pragma unroll
        for (int i = 0; i < 4; ++i) a[i] = *(const bf16x8*)(sA + (wr * 64 + i * 16 + l15) * 32 + quad * 8);
        #pragma unroll
        for (int j = 0; j < 4; ++j) b[j] = *(const bf16x8*)(sB + (wc * 64 + j * 16 + l15) * 32 + quad * 8);
        #pragma unroll
        for (int i = 0; i < 4; ++i)
            #pragma unroll
            for (int j = 0; j < 4; ++j)
                acc[i][j] = __builtin_amdgcn_mfma_f32_16x16x32_bf16(a[i], b[j], acc[i][j], 0, 0, 0);
        __syncthreads();
    }

    float* sg = sigma + (size_t)n * Dd * Dd;
    #pragma unroll
    for (int i = 0; i < 4; ++i)
        #pragma unroll
        for (int j = 0; j < 4; ++j)
            #pragma unroll
            for (int r = 0; r < 4; ++r) {
                int row = tr * 128 + wr * 64 + i * 16 + quad * 4 + r;
                int col = tc * 128 + wc * 64 + j * 16 + l15;
                sg[row * Dd + col] = acc[i][j][r];
            }
}

// ---------------------------------------------------------------------------
// Fused NS chain: one block (1024 thr, 16 waves) per batch.
// Phase 0: trace + S split (Sh,Sl) + P1 = 1.5I - 0.5S.
// Then 3x { Q = P@P ; E = 1.5I - 0.5(Q@Sh + Q@Sl) [over Q] ; P' = P@E [over P] }
// with last P-step scaled by rtr (W). All intermediates per-batch, L2-hot.
// LDS: 2 double-buffered 256x64 bf16 panels (A,B), XOR-swizzled.
// ---------------------------------------------------------------------------
__device__ __forceinline__ void stage_panel(const u16* __restrict__ g, u16* s, int tid) {
    const int wv = tid >> 6, l = tid & 63;
    const int rl = l >> 3;
    const int gch = (l & 7) ^ rl;  // inverse swizzle on global source (rule #21)
    u16* base = s + wv * 512;      // wave-uniform LDS base; lane writes +l*16B linearly
    const u16* g0 = g + (size_t)(wv * 8 + rl) * 256 + gch * 8;
    glds16(g0, base);                       // rows [wv*8, wv*8+8)
    glds16(g0 + 128 * 256, base + 8192);    // rows [128+wv*8, ...)
}

__device__ __forceinline__ bf16x8 fragr(const u16* s, int row, int kc) {
    // swizzled read: chunk ^= row&7  ->  2-way bank aliasing (free)
    return *(const bf16x8*)(s + row * 64 + ((kc ^ (row & 7)) << 3));
}

template<bool SAME, bool SPLIT, int MODE>
__device__ __forceinline__ void gemm256(const u16* __restrict__ gA,
                                        const u16* __restrict__ gBh,
                                        const u16* __restrict__ gBl,
                                        u16* __restrict__ dst, float rs,
                                        u16* sbuf, int tid) {
    const int lane = tid & 63, wave = tid >> 6;
    const int wr = wave >> 2, wc = wave & 3;         // 4x4 waves of 64x64 tiles
    const int l15 = lane & 15, quad = lane >> 4;

    f32x4 acc[4][4];
    #pragma unroll
    for (int i = 0; i < 4; ++i)
        #pragma unroll
        for (int j = 0; j < 4; ++j) acc[i][j] = (f32x4){0.f, 0.f, 0.f, 0.f};

    __syncthreads();  // drain previous epilogue stores; LDS free
    constexpr int NP = SPLIT ? 8 : 4;
    stage_panel(gA, sbuf, tid);
    if (!SAME) stage_panel(gBh, sbuf + 16384, tid);
    __syncthreads();

    for (int p = 0; p < NP; ++p) {
        const int b = p & 1;
        if (p + 1 < NP) {
            const int kn = (SPLIT ? ((p + 1) & 3) : (p + 1)) * 64;
            u16* nb = sbuf + (b ^ 1) * 32768;
            stage_panel(gA + kn, nb, tid);
            if (!SAME) {
                const u16* gsrc = (SPLIT && (p + 1) >= 4) ? gBl : gBh;
                stage_panel(gsrc + kn, nb + 16384, tid);
            }
        }
        const u16* cA = sbuf + b * 32768;
        const u16* cB = SAME ? cA : (cA + 16384);
        #pragma unroll
        for (int ks = 0; ks < 2; ++ks) {
            bf16x8 af[4], bfr[4];
            #pragma unroll
            for (int i = 0; i < 4; ++i) af[i] = fragr(cA, wr * 64 + i * 16 + l15, ks * 4 + quad);
            #pragma unroll
            for (int j = 0; j < 4; ++j) bfr[j] = fragr(cB, wc * 64 + j * 16 + l15, ks * 4 + quad);
            #pragma unroll
            for (int i = 0; i < 4; ++i)
                #pragma unroll
                for (int j = 0; j < 4; ++j)
                    acc[i][j] = __builtin_amdgcn_mfma_f32_16x16x32_bf16(af[i], bfr[j], acc[i][j], 0, 0, 0);
        }
        __syncthreads();  // next panel staged + LDS reuse safe
    }

    #pragma unroll
    for (int i = 0; i < 4; ++i)
        #pragma unroll
        for (int j = 0; j < 4; ++j)
            #pragma unroll
            for (int r = 0; r < 4; ++r) {
                int row = wr * 64 + i * 16 + quad * 4 + r;
                int col = wc * 64 + j * 16 + l15;
                float v = acc[i][j][r];
                float o;
                if (MODE == 0) o = v;
                else if (MODE == 1) o = ((row == col) ? 1.5f : 0.0f) - 0.5f * v;
                else o = v * rs;
                dst[row * 256 + col] = f2b(o);
            }
}

__global__ __launch_bounds__(1024) void ns_chain_kernel(const float* __restrict__ sigma,
                                                        u16* __restrict__ PQ,
                                                        u16* __restrict__ Sh,
                                                        u16* __restrict__ Sl) {
    __shared__ u16 sPan[4][16384];  // 128 KiB: [buf0A, buf0B, buf1A, buf1B]
    float* red = (float*)&sPan[0][0];

    const int n = blockIdx.x;
    const int tid = threadIdx.x;

    const float* sg = sigma + (size_t)n * 65536;
    u16* P = PQ + (size_t)n * 131072;   // per-batch 256 KiB: [P | QE]
    u16* QE = P + 65536;
    u16* shp = Sh + (size_t)n * 65536;
    u16* slp = Sl + (size_t)n * 65536;

    // ---- phase 0: trace reduce, split S, P1 ----
    if (tid < 256) red[tid] = sg[tid * 257];
    __syncthreads();
    for (int s = 128; s > 0; s >>= 1) {
        if (tid < s) red[tid] += red[tid + s];
        __syncthreads();
    }
    const float inv = 1.0f / red[0];
    const float rtr = sqrtf(511.0f * inv);

    #pragma unroll 4
    for (int it = 0; it < 16; ++it) {
        int idx = it * 4096 + tid * 4;
        float4 v = *(const float4*)(sg + idx);
        int row = idx >> 8, col0 = idx & 255;
        float s0 = v.x * inv, s1 = v.y * inv, s2 = v.z * inv, s3 = v.w * inv;
        u16 h0 = f2b(s0), h1 = f2b(s1), h2 = f2b(s2), h3 = f2b(s3);
        *(uint2*)(shp + idx) = make_uint2((u32)h0 | ((u32)h1 << 16), (u32)h2 | ((u32)h3 << 16));
        u16 e0 = f2b(s0 - b2f(h0)), e1 = f2b(s1 - b2f(h1));
        u16 e2 = f2b(s2 - b2f(h2)), e3 = f2b(s3 - b2f(h3));
        *(uint2*)(slp + idx) = make_uint2((u32)e0 | ((u32)e1 << 16), (u32)e2 | ((u32)e3 << 16));
        u16 p0 = f2b(((row == col0 + 0) ? 1.5f : 0.f) - 0.5f * s0);
        u16 p1 = f2b(((row == col0 + 1) ? 1.5f : 0.f) - 0.5f * s1);
        u16 p2 = f2b(((row == col0 + 2) ? 1.5f : 0.f) - 0.5f * s2);
        u16 p3 = f2b(((row == col0 + 3) ? 1.5f : 0.f) - 0.5f * s3);
        *(uint2*)(P + idx) = make_uint2((u32)p0 | ((u32)p1 << 16), (u32)p2 | ((u32)p3 << 16));
    }
    // gemm256 entry __syncthreads() drains these stores before staging reads.

    u16* sbuf = &sPan[0][0];
    #pragma unroll 1
    for (int it = 0; it < 3; ++it) {
        gemm256<true, false, 0>(P, P, (const u16*)nullptr, QE, 0.f, sbuf, tid);     // Q = P@P
        gemm256<false, true, 1>(QE, shp, slp, QE, 0.f, sbuf, tid);                  // E over Q
        if (it < 2)
            gemm256<false, false, 0>(P, QE, (const u16*)nullptr, P, 0.f, sbuf, tid); // P' over P
        else
            gemm256<false, false, 2>(P, QE, (const u16*)nullptr, P, rtr, sbuf, tid); // W over P
    }
}

// ---------------------------------------------------------------------------
// Kernel 5: out = Xn @ W (W symmetric bf16, per-batch stride 131072). fp32 out.
// ---------------------------------------------------------------------------
__global__ __launch_bounds__(256) void final_gemm(const u16* __restrict__ xn,
                                                  const u16* __restrict__ Wh,
                                                  float* __restrict__ out) {
    __shared__ u16 sA[128 * 32];
    __shared__ u16 sB[128 * 32];
    const int bid = blockIdx.x;
    const int xcd = bid & 7, slot = bid >> 3;
    const int t = slot & 7;
    const int n = ((slot >> 3) << 3) | xcd;
    const int tr = t >> 1, tc = t & 1;
    const int tid = threadIdx.x;
    const int lane = tid & 63, wave = tid >> 6;
    const int wr = wave >> 1, wc = wave & 1;
    const int l15 = lane & 15, quad = lane >> 4;
    const int row0 = tid >> 2, q = tid & 3;
    const int wb8 = (tid & 192) * 8;

    const u16* gA = xn + (size_t)n * Mm * Dd + (size_t)(tr * 128) * Dd;
    const u16* gB = Wh + (size_t)n * 131072 + (size_t)(tc * 128) * Dd;

    f32x4 acc[4][4];
    #pragma unroll
    for (int i = 0; i < 4; ++i)
        #pragma unroll
        for (int j = 0; j < 4; ++j) acc[i][j] = (f32x4){0.f, 0.f, 0.f, 0.f};

    for (int kk = 0; kk < Dd; kk += 32) {
        glds16(gA + (size_t)row0 * Dd + kk + q * 8, sA + wb8);
        glds16(gA + (size_t)(row0 + 64) * Dd + kk + q * 8, sA + 2048 + wb8);
        glds16(gB + (size_t)row0 * Dd + kk + q * 8, sB + wb8);
        glds16(gB + (size_t)(row0 + 64) * Dd + kk + q * 8, sB + 2048 + wb8);
        __syncthreads();
        bf16x8 a[4], b[4];
        #pragma unroll
        for (int i = 0; i < 4; ++i) a[i] = *(const bf16x8*)(sA + (wr * 64 + i * 16 + l15) * 32 + quad * 8);
        #pragma unroll
        for (int j = 0; j < 4; ++j) b[j] = *(const bf16x8*)(sB + (wc * 64 + j * 16 + l15) * 32 + quad * 8);
        #pragma unroll
        for (int i = 0; i < 4; ++i)
            #pragma unroll
            for (int j = 0; j < 4; ++j)
                acc[i][j] = __builtin_amdgcn_mfma_f32_16x16x32_bf16(a[i], b[j], acc[i][j], 0, 0, 0);
        __syncthreads();
    }

    float* ob = out + (size_t)n * Mm * Dd;
    #pragma unroll
    for (int i = 0; i < 4; ++i)
        #pragma unroll
        for (int j = 0; j < 4; ++j)
            #pragma unroll
            for (int r = 0; r < 4; ++r) {
                int row = tr * 128 + wr * 64 + i * 16 + quad * 4 + r;
                int col = tc * 128 + wc * 64 + j * 16 + l15;
                ob[(size_t)row * Dd + col] = acc[i][j][r];
            }
}

// ---------------------------------------------------------------------------
// Workspace (32MB units):
//  u0-1 xn | u2-3 xnT (dead after sigma) -> PQ region (256 batches x 256 KiB)
//  u4-5 sigma fp32 | u6 Sh | u7 Sl | u9 meanPart(1MB)
// ---------------------------------------------------------------------------
extern "C" void kernel_launch(void* const* d_in, const int* in_sizes, int n_in,
                              void* d_out, int out_size, void* d_ws, size_t ws_size,
                              hipStream_t stream) {
    const float* x = (const float*)d_in[0];
    float* out = (float*)d_out;
    char* ws = (char*)d_ws;
    const size_t MB32 = 33554432;

    u16* xn = (u16*)(ws + 0);
    u16* xnT = (u16*)(ws + 2 * MB32);
    u16* PQ = (u16*)(ws + 2 * MB32);   // alias xnT (dead after sigma)
    float* sigma = (float*)(ws + 4 * MB32);
    u16* Sh = (u16*)(ws + 6 * MB32);
    u16* Sl = (u16*)(ws + 7 * MB32);
    float* meanPart = (float*)(ws + 9 * MB32);

    mean_part_kernel<<<Nn * 4, 256, 0, stream>>>(x, meanPart);
    center_tr_kernel<<<Nn * 8, 256, 0, stream>>>(x, meanPart, xn, xnT);
    sigma_kernel<<<Nn * 4, 256, 0, stream>>>(xnT, sigma);
    ns_chain_kernel<<<Nn, 1024, 0, stream>>>(sigma, PQ, Sh, Sl);
    final_gemm<<<Nn * 8, 256, 0, stream>>>(xn, PQ, out);
}

// Round 2
// 771.593 us; speedup vs baseline: 1.3467x; 1.3467x over previous
//
#include <hip/hip_runtime.h>
#include <stdint.h>

#define Nn 256
#define Mm 512
#define Dd 256

typedef unsigned short u16;
typedef unsigned int u32;
typedef __attribute__((ext_vector_type(8))) short bf16x8;
typedef __attribute__((ext_vector_type(4))) float f32x4;

__device__ __forceinline__ u16 f2b(float f) {
    unsigned u = __float_as_uint(f);
    return (u16)((u + 0x7FFFu + ((u >> 16) & 1u)) >> 16);  // RNE to bf16
}
__device__ __forceinline__ float b2f(u16 h) {
    return __uint_as_float(((unsigned)h) << 16);
}
__device__ __forceinline__ u32 pk2(float lo, float hi) {
    return (u32)f2b(lo) | ((u32)f2b(hi) << 16);
}
__device__ __forceinline__ void glds16(const u16* g, u16* l) {
    __builtin_amdgcn_global_load_lds((const __attribute__((address_space(1))) void*)g,
                                     (__attribute__((address_space(3))) void*)l, 16, 0, 0);
}

// ---------------------------------------------------------------------------
// Kernel 1a: partial column sums. grid = Nn*4; block (n, c) sums 128 rows.
// ---------------------------------------------------------------------------
__global__ __launch_bounds__(256) void mean_part_kernel(const float* __restrict__ x,
                                                        float* __restrict__ meanPart) {
    const int bid = blockIdx.x;
    const int n = bid >> 2, c = bid & 3;
    const int tid = threadIdx.x;
    const float* xb = x + (size_t)n * Mm * Dd + (size_t)c * 128 * Dd;
    float a0 = 0.f, a1 = 0.f, a2 = 0.f, a3 = 0.f;
    for (int m = 0; m < 128; m += 4) {
        a0 += xb[(m + 0) * Dd + tid];
        a1 += xb[(m + 1) * Dd + tid];
        a2 += xb[(m + 2) * Dd + tid];
        a3 += xb[(m + 3) * Dd + tid];
    }
    meanPart[((size_t)n * 4 + c) * Dd + tid] = a0 + a1 + a2 + a3;
}

// ---------------------------------------------------------------------------
// Kernel 1b: center + emit xn bf16 [n][m][d] and xnT bf16 [n][d][m].
// ---------------------------------------------------------------------------
__global__ __launch_bounds__(256) void center_tr_kernel(const float* __restrict__ x,
                                                        const float* __restrict__ meanPart,
                                                        u16* __restrict__ xn,
                                                        u16* __restrict__ xnT) {
    __shared__ float meanS[Dd];
    __shared__ u16 tileS[64 * 66];
    const int bid = blockIdx.x;
    const int n = bid >> 3, mt = bid & 7;
    const int tid = threadIdx.x;

    const float* mp = meanPart + (size_t)n * 4 * Dd;
    meanS[tid] = (mp[tid] + mp[Dd + tid] + mp[2 * Dd + tid] + mp[3 * Dd + tid]) * (1.0f / Mm);
    __syncthreads();

    const float* xb = x + (size_t)n * Mm * Dd;
    u16* xnb = xn + (size_t)n * Mm * Dd;
    u16* xtb = xnT + (size_t)n * Dd * Mm;
    const int mrow = tid >> 4, dq = tid & 15;
    const int tx2 = (tid & 31) * 2, ty = tid >> 5;

    for (int dt = 0; dt < Dd / 64; ++dt) {
        #pragma unroll
        for (int rr = 0; rr < 4; ++rr) {
            int ml = mrow + 16 * rr;
            int m = mt * 64 + ml;
            int d = dt * 64 + dq * 4;
            float4 v = *(const float4*)(xb + (size_t)m * Dd + d);
            float4 mu = *(const float4*)(meanS + d);
            u16 b0 = f2b(v.x - mu.x), b1 = f2b(v.y - mu.y);
            u16 b2 = f2b(v.z - mu.z), b3 = f2b(v.w - mu.w);
            u32 lo = (u32)b0 | ((u32)b1 << 16);
            u32 hi = (u32)b2 | ((u32)b3 << 16);
            *(uint2*)(xnb + (size_t)m * Dd + d) = make_uint2(lo, hi);
            tileS[(dq * 4 + 0) * 66 + ml] = b0;
            tileS[(dq * 4 + 1) * 66 + ml] = b1;
            tileS[(dq * 4 + 2) * 66 + ml] = b2;
            tileS[(dq * 4 + 3) * 66 + ml] = b3;
        }
        __syncthreads();
        #pragma unroll
        for (int r = 0; r < 8; ++r) {
            int dl = r * 8 + ty;
            u32 w = *(const u32*)(tileS + dl * 66 + tx2);
            *(u32*)(xtb + (size_t)(dt * 64 + dl) * Mm + mt * 64 + tx2) = w;
        }
        __syncthreads();
    }
}

// ---------------------------------------------------------------------------
// Kernel 2: sigma[n] = XnT @ XnT^T (raw fp32). XCD-swizzled.
// ---------------------------------------------------------------------------
__global__ __launch_bounds__(256) void sigma_kernel(const u16* __restrict__ xnT,
                                                    float* __restrict__ sigma) {
    __shared__ u16 sA[128 * 32];
    __shared__ u16 sB[128 * 32];
    const int bid = blockIdx.x;
    const int xcd = bid & 7, slot = bid >> 3;
    const int t = slot & 3;
    const int n = ((slot >> 2) << 3) | xcd;
    const int tr = t >> 1, tc = t & 1;
    const int tid = threadIdx.x;
    const int lane = tid & 63, wave = tid >> 6;
    const int wr = wave >> 1, wc = wave & 1;
    const int l15 = lane & 15, quad = lane >> 4;
    const int row0 = tid >> 2, q = tid & 3;
    const int wb8 = (tid & 192) * 8;

    const u16* base = xnT + (size_t)n * Dd * Mm;
    const u16* gA = base + (size_t)(tr * 128) * Mm;
    const u16* gB = base + (size_t)(tc * 128) * Mm;

    f32x4 acc[4][4];
    #pragma unroll
    for (int i = 0; i < 4; ++i)
        #pragma unroll
        for (int j = 0; j < 4; ++j) acc[i][j] = (f32x4){0.f, 0.f, 0.f, 0.f};

    for (int kk = 0; kk < Mm; kk += 32) {
        glds16(gA + (size_t)row0 * Mm + kk + q * 8, sA + wb8);
        glds16(gA + (size_t)(row0 + 64) * Mm + kk + q * 8, sA + 2048 + wb8);
        glds16(gB + (size_t)row0 * Mm + kk + q * 8, sB + wb8);
        glds16(gB + (size_t)(row0 + 64) * Mm + kk + q * 8, sB + 2048 + wb8);
        __syncthreads();
        bf16x8 a[4], b[4];
        #pragma unroll
        for (int i = 0; i < 4; ++i) a[i] = *(const bf16x8*)(sA + (wr * 64 + i * 16 + l15) * 32 + quad * 8);
        #pragma unroll
        for (int j = 0; j < 4; ++j) b[j] = *(const bf16x8*)(sB + (wc * 64 + j * 16 + l15) * 32 + quad * 8);
        #pragma unroll
        for (int i = 0; i < 4; ++i)
            #pragma unroll
            for (int j = 0; j < 4; ++j)
                acc[i][j] = __builtin_amdgcn_mfma_f32_16x16x32_bf16(a[i], b[j], acc[i][j], 0, 0, 0);
        __syncthreads();
    }

    float* sg = sigma + (size_t)n * Dd * Dd;
    #pragma unroll
    for (int i = 0; i < 4; ++i)
        #pragma unroll
        for (int j = 0; j < 4; ++j)
            #pragma unroll
            for (int r = 0; r < 4; ++r) {
                int row = tr * 128 + wr * 64 + i * 16 + quad * 4 + r;
                int col = tc * 128 + wc * 64 + j * 16 + l15;
                sg[row * Dd + col] = acc[i][j][r];
            }
}

// ---------------------------------------------------------------------------
// Fused NS chain v2: one block (1024 thr, 16 waves) per batch.
// P persists in LDS (swizzled); Q and P3 persist in registers (bf16) and are
// exchanged via a 32KB k-strip region. Only S (Sh/Sl) streams from global.
// Per iteration: Q = P@P ; P3 = P@Q ; P' = 1.5P - 0.5*P3@(Sh+Sl).
// LDS map (u16 units): P [0,65536) ; strips [65536,81920):
//   g2: sQ  = 2 x [128][40]  (double-buffered, padded stride 80B)
//   g3: sA  = [256][32] XOR-swizzled ; sSh/sSl = [128][32] each (glds-linear,
//       source-chunk pre-swizzled)
// ---------------------------------------------------------------------------
__device__ __forceinline__ bf16x8 ldP(const u16* Plds, int row, int ch) {
    // chunk (16B) swizzle: slot = ch ^ (row&7) -> 2-way bank alias (free)
    return *(const bf16x8*)(Plds + row * 256 + ((ch ^ (row & 7)) << 3));
}

__device__ __forceinline__ void dumpQ(u16* buf, const u32* qbf, int jp, int s,
                                      int wr, int wc, int quad, int l15) {
    if (wc != (s >> 1)) return;
    #pragma unroll
    for (int i2 = 0; i2 < 2; ++i2)
        #pragma unroll
        for (int jj = 0; jj < 2; ++jj) {
            int j_ = (s & 1) * 2 + jj;
            #pragma unroll
            for (int rh = 0; rh < 2; ++rh) {
                u32 w = qbf[((2 * jp + i2) * 4 + j_) * 2 + rh];
                int bufRow = wr * 32 + i2 * 16 + quad * 4 + rh * 2;
                buf[(bufRow + 0) * 40 + jj * 16 + l15] = (u16)(w & 0xffffu);
                buf[(bufRow + 1) * 40 + jj * 16 + l15] = (u16)(w >> 16);
            }
        }
}

__device__ __forceinline__ void dumpA(u16* sA, const u32* p3bf, int s,
                                      int wr, int wc, int quad, int l15) {
    if (wc != (s >> 1)) return;
    #pragma unroll
    for (int i = 0; i < 4; ++i)
        #pragma unroll
        for (int jj = 0; jj < 2; ++jj) {
            int j_ = (s & 1) * 2 + jj;
            int kIdx = jj * 16 + l15;
            int ch = kIdx >> 3;
            #pragma unroll
            for (int rh = 0; rh < 2; ++rh) {
                u32 w = p3bf[(i * 4 + j_) * 2 + rh];
                int r0 = wr * 64 + i * 16 + quad * 4 + rh * 2;
                sA[(r0 + 0) * 32 + ((ch ^ ((r0 + 0) & 3)) << 3) + (kIdx & 7)] = (u16)(w & 0xffffu);
                sA[(r0 + 1) * 32 + ((ch ^ ((r0 + 1) & 3)) << 3) + (kIdx & 7)] = (u16)(w >> 16);
            }
        }
}

__device__ __forceinline__ void stageS(u16* sS, const u16* shp, const u16* slp,
                                       int jp, int s, int wave, int lane) {
    int w = wave & 7;
    int bufRow = w * 16 + (lane >> 2);
    int c = lane & 3;
    int gR = ((bufRow >> 5) << 6) + jp * 32 + (bufRow & 31);
    const u16* srcb = (wave < 8) ? shp : slp;
    const u16* src = srcb + gR * 256 + (s * 4 + (c ^ (bufRow & 3))) * 8;
    u16* dst = sS + ((wave < 8) ? 0 : 4096) + w * 512;
    glds16(src, dst);
}

__global__ __launch_bounds__(1024) void ns_chain_kernel(const float* __restrict__ sigma,
                                                        u16* __restrict__ Wg,
                                                        u16* __restrict__ Sh,
                                                        u16* __restrict__ Sl) {
    __shared__ __align__(16) u16 lds[81920];   // 160 KB
    u16* Plds = lds;
    u16* strips = lds + 65536;

    const int n = blockIdx.x, tid = threadIdx.x;
    const int lane = tid & 63, wave = tid >> 6;
    const int l15 = lane & 15, quad = lane >> 4;
    const int wr = wave >> 2, wc = wave & 3;

    const float* sg = sigma + (size_t)n * 65536;
    u16* shp = Sh + (size_t)n * 65536;
    u16* slp = Sl + (size_t)n * 65536;

    // ---- phase 0: trace, split S -> global, P1 -> LDS (swizzled) ----
    float* red = (float*)strips;
    if (tid < 256) red[tid] = sg[tid * 257];
    __syncthreads();
    for (int s = 128; s > 0; s >>= 1) {
        if (tid < s) red[tid] += red[tid + s];
        __syncthreads();
    }
    const float inv = 1.0f / red[0];
    const float rtr = sqrtf(511.0f * inv);

    #pragma unroll 4
    for (int itp = 0; itp < 16; ++itp) {
        int idx = itp * 4096 + tid * 4;
        float4 v = *(const float4*)(sg + idx);
        int row = idx >> 8, col = idx & 255;
        float s0 = v.x * inv, s1 = v.y * inv, s2 = v.z * inv, s3 = v.w * inv;
        u16 h0 = f2b(s0), h1 = f2b(s1), h2 = f2b(s2), h3 = f2b(s3);
        *(uint2*)(shp + idx) = make_uint2((u32)h0 | ((u32)h1 << 16), (u32)h2 | ((u32)h3 << 16));
        u16 e0 = f2b(s0 - b2f(h0)), e1 = f2b(s1 - b2f(h1));
        u16 e2 = f2b(s2 - b2f(h2)), e3 = f2b(s3 - b2f(h3));
        *(uint2*)(slp + idx) = make_uint2((u32)e0 | ((u32)e1 << 16), (u32)e2 | ((u32)e3 << 16));
        u16 p0 = f2b(((row == col + 0) ? 1.5f : 0.f) - 0.5f * s0);
        u16 p1 = f2b(((row == col + 1) ? 1.5f : 0.f) - 0.5f * s1);
        u16 p2 = f2b(((row == col + 2) ? 1.5f : 0.f) - 0.5f * s2);
        u16 p3 = f2b(((row == col + 3) ? 1.5f : 0.f) - 0.5f * s3);
        int pa = row * 256 + (((col >> 3) ^ (row & 7)) << 3) + (col & 7);
        *(uint2*)(Plds + pa) = make_uint2((u32)p0 | ((u32)p1 << 16), (u32)p2 | ((u32)p3 << 16));
    }
    __syncthreads();

    // ---- 3 NS iterations ----
    #pragma unroll 1
    for (int it = 0; it < 3; ++it) {
        const bool last = (it == 2);
        u32 qbf[32], p3bf[32];

        // ---- g1: Q = P@P (pure LDS-P reads, no barriers in K-loop) ----
        {
            f32x4 acc1[4][4];
            #pragma unroll
            for (int i = 0; i < 4; ++i)
                #pragma unroll
                for (int j = 0; j < 4; ++j) acc1[i][j] = (f32x4){0.f, 0.f, 0.f, 0.f};
            #pragma unroll
            for (int s = 0; s < 8; ++s) {
                bf16x8 a[4], b[4];
                #pragma unroll
                for (int i = 0; i < 4; ++i) a[i] = ldP(Plds, wr * 64 + i * 16 + l15, s * 4 + quad);
                #pragma unroll
                for (int j = 0; j < 4; ++j) b[j] = ldP(Plds, wc * 64 + j * 16 + l15, s * 4 + quad);
                #pragma unroll
                for (int i = 0; i < 4; ++i)
                    #pragma unroll
                    for (int j = 0; j < 4; ++j)
                        acc1[i][j] = __builtin_amdgcn_mfma_f32_16x16x32_bf16(a[i], b[j], acc1[i][j], 0, 0, 0);
            }
            #pragma unroll
            for (int i = 0; i < 4; ++i)
                #pragma unroll
                for (int j = 0; j < 4; ++j)
                    #pragma unroll
                    for (int rh = 0; rh < 2; ++rh)
                        qbf[(i * 4 + j) * 2 + rh] = pk2(acc1[i][j][2 * rh], acc1[i][j][2 * rh + 1]);
        }

        // ---- g2: P3 = P@Q (A from LDS-P, B = Q via reg->LDS strips) ----
        {
            u16* sQ = strips;  // 2 x [128][40]
            #pragma unroll
            for (int jp = 0; jp < 2; ++jp) {
                f32x4 acc2[4][2];
                #pragma unroll
                for (int i = 0; i < 4; ++i)
                    #pragma unroll
                    for (int jj = 0; jj < 2; ++jj) acc2[i][jj] = (f32x4){0.f, 0.f, 0.f, 0.f};
                dumpQ(sQ, qbf, jp, 0, wr, wc, quad, l15);
                __syncthreads();
                #pragma unroll
                for (int s = 0; s < 8; ++s) {
                    u16* cur = sQ + (s & 1) * 5120;
                    bf16x8 a[4];
                    #pragma unroll
                    for (int i = 0; i < 4; ++i) a[i] = ldP(Plds, wr * 64 + i * 16 + l15, s * 4 + quad);
                    bf16x8 b[2];
                    #pragma unroll
                    for (int jj = 0; jj < 2; ++jj)
                        b[jj] = *(const bf16x8*)(cur + (wc * 32 + jj * 16 + l15) * 40 + quad * 8);
                    #pragma unroll
                    for (int i = 0; i < 4; ++i)
                        #pragma unroll
                        for (int jj = 0; jj < 2; ++jj)
                            acc2[i][jj] = __builtin_amdgcn_mfma_f32_16x16x32_bf16(a[i], b[jj], acc2[i][jj], 0, 0, 0);
                    if (s < 7) dumpQ(sQ + (((s + 1) & 1) * 5120), qbf, jp, s + 1, wr, wc, quad, l15);
                    __syncthreads();
                }
                #pragma unroll
                for (int i = 0; i < 4; ++i)
                    #pragma unroll
                    for (int jj = 0; jj < 2; ++jj)
                        #pragma unroll
                        for (int rh = 0; rh < 2; ++rh)
                            p3bf[(i * 4 + 2 * jp + jj) * 2 + rh] =
                                pk2(acc2[i][jj][2 * rh], acc2[i][jj][2 * rh + 1]);
            }
        }

        // ---- g3: P' = 1.5P - 0.5*P3@(Sh+Sl); last iter: W = rtr*P' ----
        {
            u16* sA = strips;         // [256][32] swizzled
            u16* sS = strips + 8192;  // [128][32] h + [128][32] l
            #pragma unroll
            for (int jp = 0; jp < 2; ++jp) {
                f32x4 acc3[4][2];
                #pragma unroll
                for (int i = 0; i < 4; ++i)
                    #pragma unroll
                    for (int jj = 0; jj < 2; ++jj) acc3[i][jj] = (f32x4){0.f, 0.f, 0.f, 0.f};
                #pragma unroll
                for (int s = 0; s < 8; ++s) {
                    dumpA(sA, p3bf, s, wr, wc, quad, l15);
                    stageS(sS, shp, slp, jp, s, wave, lane);
                    __syncthreads();  // drains lgkm + vmcnt
                    bf16x8 a[4];
                    #pragma unroll
                    for (int i = 0; i < 4; ++i) {
                        int r_ = wr * 64 + i * 16 + l15;
                        a[i] = *(const bf16x8*)(sA + r_ * 32 + ((quad ^ (r_ & 3)) << 3));
                    }
                    #pragma unroll
                    for (int jj = 0; jj < 2; ++jj) {
                        int br = wc * 32 + jj * 16 + l15;
                        bf16x8 bh = *(const bf16x8*)(sS + br * 32 + ((quad ^ (br & 3)) << 3));
                        bf16x8 bl = *(const bf16x8*)(sS + 4096 + br * 32 + ((quad ^ (br & 3)) << 3));
                        #pragma unroll
                        for (int i = 0; i < 4; ++i)
                            acc3[i][jj] = __builtin_amdgcn_mfma_f32_16x16x32_bf16(a[i], bh, acc3[i][jj], 0, 0, 0);
                        #pragma unroll
                        for (int i = 0; i < 4; ++i)
                            acc3[i][jj] = __builtin_amdgcn_mfma_f32_16x16x32_bf16(a[i], bl, acc3[i][jj], 0, 0, 0);
                    }
                    __syncthreads();  // reads done before next dump/stage
                }
                // epilogue: own-tile only (disjoint across waves/passes)
                if (last) {
                    u16* wg = Wg + (size_t)n * 65536;
                    #pragma unroll
                    for (int i = 0; i < 4; ++i)
                        #pragma unroll
                        for (int jj = 0; jj < 2; ++jj)
                            #pragma unroll
                            for (int r = 0; r < 4; ++r) {
                                int row = wr * 64 + i * 16 + quad * 4 + r;
                                int col = wc * 64 + (2 * jp + jj) * 16 + l15;
                                int pa = row * 256 + (((col >> 3) ^ (row & 7)) << 3) + (col & 7);
                                float pv = 1.5f * b2f(Plds[pa]) - 0.5f * acc3[i][jj][r];
                                wg[row * 256 + col] = f2b(pv * rtr);
                            }
                } else {
                    #pragma unroll
                    for (int i = 0; i < 4; ++i)
                        #pragma unroll
                        for (int jj = 0; jj < 2; ++jj)
                            #pragma unroll
                            for (int r = 0; r < 4; ++r) {
                                int row = wr * 64 + i * 16 + quad * 4 + r;
                                int col = wc * 64 + (2 * jp + jj) * 16 + l15;
                                int pa = row * 256 + (((col >> 3) ^ (row & 7)) << 3) + (col & 7);
                                float pv = 1.5f * b2f(Plds[pa]) - 0.5f * acc3[i][jj][r];
                                Plds[pa] = f2b(pv);
                            }
                }
            }
            __syncthreads();  // P fully updated before next iteration's g1
        }
    }
}

// ---------------------------------------------------------------------------
// Kernel 5: out = Xn @ W (W symmetric bf16, stride 65536). fp32 out.
// ---------------------------------------------------------------------------
__global__ __launch_bounds__(256) void final_gemm(const u16* __restrict__ xn,
                                                  const u16* __restrict__ Wh,
                                                  float* __restrict__ out) {
    __shared__ u16 sA[128 * 32];
    __shared__ u16 sB[128 * 32];
    const int bid = blockIdx.x;
    const int xcd = bid & 7, slot = bid >> 3;
    const int t = slot & 7;
    const int n = ((slot >> 3) << 3) | xcd;
    const int tr = t >> 1, tc = t & 1;
    const int tid = threadIdx.x;
    const int lane = tid & 63, wave = tid >> 6;
    const int wr = wave >> 1, wc = wave & 1;
    const int l15 = lane & 15, quad = lane >> 4;
    const int row0 = tid >> 2, q = tid & 3;
    const int wb8 = (tid & 192) * 8;

    const u16* gA = xn + (size_t)n * Mm * Dd + (size_t)(tr * 128) * Dd;
    const u16* gB = Wh + (size_t)n * Dd * Dd + (size_t)(tc * 128) * Dd;

    f32x4 acc[4][4];
    #pragma unroll
    for (int i = 0; i < 4; ++i)
        #pragma unroll
        for (int j = 0; j < 4; ++j) acc[i][j] = (f32x4){0.f, 0.f, 0.f, 0.f};

    for (int kk = 0; kk < Dd; kk += 32) {
        glds16(gA + (size_t)row0 * Dd + kk + q * 8, sA + wb8);
        glds16(gA + (size_t)(row0 + 64) * Dd + kk + q * 8, sA + 2048 + wb8);
        glds16(gB + (size_t)row0 * Dd + kk + q * 8, sB + wb8);
        glds16(gB + (size_t)(row0 + 64) * Dd + kk + q * 8, sB + 2048 + wb8);
        __syncthreads();
        bf16x8 a[4], b[4];
        #pragma unroll
        for (int i = 0; i < 4; ++i) a[i] = *(const bf16x8*)(sA + (wr * 64 + i * 16 + l15) * 32 + quad * 8);
        #pragma unroll
        for (int j = 0; j < 4; ++j) b[j] = *(const bf16x8*)(sB + (wc * 64 + j * 16 + l15) * 32 + quad * 8);
        #pragma unroll
        for (int i = 0; i < 4; ++i)
            #pragma unroll
            for (int j = 0; j < 4; ++j)
                acc[i][j] = __builtin_amdgcn_mfma_f32_16x16x32_bf16(a[i], b[j], acc[i][j], 0, 0, 0);
        __syncthreads();
    }

    float* ob = out + (size_t)n * Mm * Dd;
    #pragma unroll
    for (int i = 0; i < 4; ++i)
        #pragma unroll
        for (int j = 0; j < 4; ++j)
            #pragma unroll
            for (int r = 0; r < 4; ++r) {
                int row = tr * 128 + wr * 64 + i * 16 + quad * 4 + r;
                int col = tc * 128 + wc * 64 + j * 16 + l15;
                ob[(size_t)row * Dd + col] = acc[i][j][r];
            }
}

// ---------------------------------------------------------------------------
// Workspace (32MB units):
//  u0-1 xn | u2-3 xnT (dead after sigma) -> W at u2 (32MB)
//  u4-5 sigma fp32 | u6 Sh | u7 Sl | u9 meanPart
// ---------------------------------------------------------------------------
extern "C" void kernel_launch(void* const* d_in, const int* in_sizes, int n_in,
                              void* d_out, int out_size, void* d_ws, size_t ws_size,
                              hipStream_t stream) {
    const float* x = (const float*)d_in[0];
    float* out = (float*)d_out;
    char* ws = (char*)d_ws;
    const size_t MB32 = 33554432;

    u16* xn = (u16*)(ws + 0);
    u16* xnT = (u16*)(ws + 2 * MB32);
    u16* W = (u16*)(ws + 2 * MB32);    // alias xnT (dead after sigma)
    float* sigma = (float*)(ws + 4 * MB32);
    u16* Sh = (u16*)(ws + 6 * MB32);
    u16* Sl = (u16*)(ws + 7 * MB32);
    float* meanPart = (float*)(ws + 9 * MB32);

    mean_part_kernel<<<Nn * 4, 256, 0, stream>>>(x, meanPart);
    center_tr_kernel<<<Nn * 8, 256, 0, stream>>>(x, meanPart, xn, xnT);
    sigma_kernel<<<Nn * 4, 256, 0, stream>>>(xnT, sigma);
    ns_chain_kernel<<<Nn, 1024, 0, stream>>>(sigma, W, Sh, Sl);
    final_gemm<<<Nn * 8, 256, 0, stream>>>(xn, W, out);
}

// Round 3
// 724.643 us; speedup vs baseline: 1.4340x; 1.0648x over previous
//
#include <hip/hip_runtime.h>
#include <stdint.h>

#define Nn 256
#define Mm 512
#define Dd 256

typedef unsigned short u16;
typedef unsigned int u32;
typedef __attribute__((ext_vector_type(8))) short bf16x8;
typedef __attribute__((ext_vector_type(4))) float f32x4;

__device__ __forceinline__ u16 f2b(float f) {
    unsigned u = __float_as_uint(f);
    return (u16)((u + 0x7FFFu + ((u >> 16) & 1u)) >> 16);  // RNE to bf16
}
__device__ __forceinline__ float b2f(u16 h) {
    return __uint_as_float(((unsigned)h) << 16);
}
__device__ __forceinline__ u32 pk2(float lo, float hi) {
    return (u32)f2b(lo) | ((u32)f2b(hi) << 16);
}
__device__ __forceinline__ void glds16(const u16* g, u16* l) {
    __builtin_amdgcn_global_load_lds((const __attribute__((address_space(1))) void*)g,
                                     (__attribute__((address_space(3))) void*)l, 16, 0, 0);
}

// ---------------------------------------------------------------------------
// Kernel 1a: partial column sums. grid = Nn*4; block (n, c) sums 128 rows.
// ---------------------------------------------------------------------------
__global__ __launch_bounds__(256) void mean_part_kernel(const float* __restrict__ x,
                                                        float* __restrict__ meanPart) {
    const int bid = blockIdx.x;
    const int n = bid >> 2, c = bid & 3;
    const int tid = threadIdx.x;
    const float* xb = x + (size_t)n * Mm * Dd + (size_t)c * 128 * Dd;
    float a0 = 0.f, a1 = 0.f, a2 = 0.f, a3 = 0.f;
    for (int m = 0; m < 128; m += 4) {
        a0 += xb[(m + 0) * Dd + tid];
        a1 += xb[(m + 1) * Dd + tid];
        a2 += xb[(m + 2) * Dd + tid];
        a3 += xb[(m + 3) * Dd + tid];
    }
    meanPart[((size_t)n * 4 + c) * Dd + tid] = a0 + a1 + a2 + a3;
}

// ---------------------------------------------------------------------------
// Kernel 1b: center + emit xn bf16 [n][m][d] and xnT bf16 [n][d][m].
// ---------------------------------------------------------------------------
__global__ __launch_bounds__(256) void center_tr_kernel(const float* __restrict__ x,
                                                        const float* __restrict__ meanPart,
                                                        u16* __restrict__ xn,
                                                        u16* __restrict__ xnT) {
    __shared__ float meanS[Dd];
    __shared__ u16 tileS[64 * 66];
    const int bid = blockIdx.x;
    const int n = bid >> 3, mt = bid & 7;
    const int tid = threadIdx.x;

    const float* mp = meanPart + (size_t)n * 4 * Dd;
    meanS[tid] = (mp[tid] + mp[Dd + tid] + mp[2 * Dd + tid] + mp[3 * Dd + tid]) * (1.0f / Mm);
    __syncthreads();

    const float* xb = x + (size_t)n * Mm * Dd;
    u16* xnb = xn + (size_t)n * Mm * Dd;
    u16* xtb = xnT + (size_t)n * Dd * Mm;
    const int mrow = tid >> 4, dq = tid & 15;
    const int tx2 = (tid & 31) * 2, ty = tid >> 5;

    for (int dt = 0; dt < Dd / 64; ++dt) {
        #pragma unroll
        for (int rr = 0; rr < 4; ++rr) {
            int ml = mrow + 16 * rr;
            int m = mt * 64 + ml;
            int d = dt * 64 + dq * 4;
            float4 v = *(const float4*)(xb + (size_t)m * Dd + d);
            float4 mu = *(const float4*)(meanS + d);
            u16 b0 = f2b(v.x - mu.x), b1 = f2b(v.y - mu.y);
            u16 b2 = f2b(v.z - mu.z), b3 = f2b(v.w - mu.w);
            u32 lo = (u32)b0 | ((u32)b1 << 16);
            u32 hi = (u32)b2 | ((u32)b3 << 16);
            *(uint2*)(xnb + (size_t)m * Dd + d) = make_uint2(lo, hi);
            tileS[(dq * 4 + 0) * 66 + ml] = b0;
            tileS[(dq * 4 + 1) * 66 + ml] = b1;
            tileS[(dq * 4 + 2) * 66 + ml] = b2;
            tileS[(dq * 4 + 3) * 66 + ml] = b3;
        }
        __syncthreads();
        #pragma unroll
        for (int r = 0; r < 8; ++r) {
            int dl = r * 8 + ty;
            u32 w = *(const u32*)(tileS + dl * 66 + tx2);
            *(u32*)(xtb + (size_t)(dt * 64 + dl) * Mm + mt * 64 + tx2) = w;
        }
        __syncthreads();
    }
}

// ---------------------------------------------------------------------------
// Kernel 2: sigma[n] = XnT @ XnT^T (raw fp32). XCD-swizzled.
// ---------------------------------------------------------------------------
__global__ __launch_bounds__(256) void sigma_kernel(const u16* __restrict__ xnT,
                                                    float* __restrict__ sigma) {
    __shared__ u16 sA[128 * 32];
    __shared__ u16 sB[128 * 32];
    const int bid = blockIdx.x;
    const int xcd = bid & 7, slot = bid >> 3;
    const int t = slot & 3;
    const int n = ((slot >> 2) << 3) | xcd;
    const int tr = t >> 1, tc = t & 1;
    const int tid = threadIdx.x;
    const int lane = tid & 63, wave = tid >> 6;
    const int wr = wave >> 1, wc = wave & 1;
    const int l15 = lane & 15, quad = lane >> 4;
    const int row0 = tid >> 2, q = tid & 3;
    const int wb8 = (tid & 192) * 8;

    const u16* base = xnT + (size_t)n * Dd * Mm;
    const u16* gA = base + (size_t)(tr * 128) * Mm;
    const u16* gB = base + (size_t)(tc * 128) * Mm;

    f32x4 acc[4][4];
    #pragma unroll
    for (int i = 0; i < 4; ++i)
        #pragma unroll
        for (int j = 0; j < 4; ++j) acc[i][j] = (f32x4){0.f, 0.f, 0.f, 0.f};

    for (int kk = 0; kk < Mm; kk += 32) {
        glds16(gA + (size_t)row0 * Mm + kk + q * 8, sA + wb8);
        glds16(gA + (size_t)(row0 + 64) * Mm + kk + q * 8, sA + 2048 + wb8);
        glds16(gB + (size_t)row0 * Mm + kk + q * 8, sB + wb8);
        glds16(gB + (size_t)(row0 + 64) * Mm + kk + q * 8, sB + 2048 + wb8);
        __syncthreads();
        bf16x8 a[4], b[4];
        #pragma unroll
        for (int i = 0; i < 4; ++i) a[i] = *(const bf16x8*)(sA + (wr * 64 + i * 16 + l15) * 32 + quad * 8);
        #pragma unroll
        for (int j = 0; j < 4; ++j) b[j] = *(const bf16x8*)(sB + (wc * 64 + j * 16 + l15) * 32 + quad * 8);
        #pragma unroll
        for (int i = 0; i < 4; ++i)
            #pragma unroll
            for (int j = 0; j < 4; ++j)
                acc[i][j] = __builtin_amdgcn_mfma_f32_16x16x32_bf16(a[i], b[j], acc[i][j], 0, 0, 0);
        __syncthreads();
    }

    float* sg = sigma + (size_t)n * Dd * Dd;
    #pragma unroll
    for (int i = 0; i < 4; ++i)
        #pragma unroll
        for (int j = 0; j < 4; ++j)
            #pragma unroll
            for (int r = 0; r < 4; ++r) {
                int row = tr * 128 + wr * 64 + i * 16 + quad * 4 + r;
                int col = tc * 128 + wc * 64 + j * 16 + l15;
                sg[row * Dd + col] = acc[i][j][r];
            }
}

// ---------------------------------------------------------------------------
// Fused NS chain v3: one block (1024 thr, 16 waves) per batch, <=128 VGPR.
// P persists in LDS (chunk-swizzled [row][256]). Per iteration:
//   g1: Q = P@P            (64x64 tiles/wave, acc 64 f32 -> qbf 32 u32)
//   g2: P3 = P@Q           (4 col passes; Q B-panel in strip [64col][256k],
//                           uint2 dumps, conflict-free; acc 16 f32/pass)
//   g3: P' = 1.5P-.5*P3@(Sh+Sl)  (2 col passes x 8 k-panels; A from p3bf,
//                           S reg-prefetched 1 step ahead, raw barriers)
// Strips (32KB): g2 sQ[64][256] | g3 sA[256][32] + sS[2][128][32]
// ---------------------------------------------------------------------------
__device__ __forceinline__ bf16x8 ldP(const u16* Plds, int row, int ch) {
    return *(const bf16x8*)(Plds + row * 256 + ((ch ^ (row & 7)) << 3));
}

__global__ __launch_bounds__(1024, 4) void ns_chain_kernel(const float* __restrict__ sigma,
                                                           u16* __restrict__ Wg,
                                                           u16* __restrict__ Sh,
                                                           u16* __restrict__ Sl) {
    __shared__ __align__(16) u16 lds[81920];   // 160 KB
    u16* Plds = lds;
    u16* strips = lds + 65536;   // 16384 u16 = 32KB
    u16* sQ = strips;            // g2: [64][256]
    u16* sA = strips;            // g3: [256][32]
    u16* sS = strips + 8192;     // g3: Sh [128][32] + Sl [128][32]

    const int n = blockIdx.x, tid = threadIdx.x;
    const int lane = tid & 63, wave = tid >> 6;
    const int l15 = lane & 15, quad = lane >> 4;
    const int wr = wave >> 2, wc = wave & 3;

    const float* sg = sigma + (size_t)n * 65536;
    u16* shp = Sh + (size_t)n * 65536;
    u16* slp = Sl + (size_t)n * 65536;

    // ---- phase 0: trace, split S -> global, P1 -> LDS (swizzled) ----
    float* red = (float*)strips;
    if (tid < 256) red[tid] = sg[tid * 257];
    __syncthreads();
    for (int s = 128; s > 0; s >>= 1) {
        if (tid < s) red[tid] += red[tid + s];
        __syncthreads();
    }
    const float inv = 1.0f / red[0];
    const float rtr = sqrtf(511.0f * inv);

    #pragma unroll 4
    for (int itp = 0; itp < 16; ++itp) {
        int idx = itp * 4096 + tid * 4;
        float4 v = *(const float4*)(sg + idx);
        int row = idx >> 8, col = idx & 255;
        float s0 = v.x * inv, s1 = v.y * inv, s2 = v.z * inv, s3 = v.w * inv;
        u16 h0 = f2b(s0), h1 = f2b(s1), h2 = f2b(s2), h3 = f2b(s3);
        *(uint2*)(shp + idx) = make_uint2((u32)h0 | ((u32)h1 << 16), (u32)h2 | ((u32)h3 << 16));
        u16 e0 = f2b(s0 - b2f(h0)), e1 = f2b(s1 - b2f(h1));
        u16 e2 = f2b(s2 - b2f(h2)), e3 = f2b(s3 - b2f(h3));
        *(uint2*)(slp + idx) = make_uint2((u32)e0 | ((u32)e1 << 16), (u32)e2 | ((u32)e3 << 16));
        u16 p0 = f2b(((row == col + 0) ? 1.5f : 0.f) - 0.5f * s0);
        u16 p1 = f2b(((row == col + 1) ? 1.5f : 0.f) - 0.5f * s1);
        u16 p2 = f2b(((row == col + 2) ? 1.5f : 0.f) - 0.5f * s2);
        u16 p3 = f2b(((row == col + 3) ? 1.5f : 0.f) - 0.5f * s3);
        int pa = row * 256 + (((col >> 3) ^ (row & 7)) << 3) + (col & 7);
        *(uint2*)(Plds + pa) = make_uint2((u32)p0 | ((u32)p1 << 16), (u32)p2 | ((u32)p3 << 16));
    }
    __syncthreads();   // full drain: S stores visible before any re-read

    // S-staging per-lane constants: waves 0-7 stage Sh, 8-15 stage Sl.
    const u16* sBase = (wave < 8) ? shp : slp;
    const int w8 = wave & 7;
    const int cl_st = w8 * 16 + (lane >> 2);        // strip row (= S column)
    const int gch_st = (lane & 3) ^ (cl_st & 3);    // pre-swizzled src chunk
    u16* sDst = sS + ((wave < 8) ? 0 : 4096) + w8 * 512 + lane * 8;

    // ---- 3 NS iterations ----
    #pragma unroll 1
    for (int it = 0; it < 3; ++it) {
        const bool last = (it == 2);
        u32 qbf[32], p3bf[32];

        // ---- g1: Q = P@P (64x64 tile per wave, no barriers) ----
        {
            f32x4 acc1[4][4];
            #pragma unroll
            for (int i = 0; i < 4; ++i)
                #pragma unroll
                for (int j = 0; j < 4; ++j) acc1[i][j] = (f32x4){0.f, 0.f, 0.f, 0.f};
            #pragma unroll
            for (int s = 0; s < 8; ++s) {
                bf16x8 a[4], b[4];
                #pragma unroll
                for (int i = 0; i < 4; ++i) a[i] = ldP(Plds, wr * 64 + i * 16 + l15, s * 4 + quad);
                #pragma unroll
                for (int j = 0; j < 4; ++j) b[j] = ldP(Plds, wc * 64 + j * 16 + l15, s * 4 + quad);
                #pragma unroll
                for (int i = 0; i < 4; ++i)
                    #pragma unroll
                    for (int j = 0; j < 4; ++j)
                        acc1[i][j] = __builtin_amdgcn_mfma_f32_16x16x32_bf16(a[i], b[j], acc1[i][j], 0, 0, 0);
            }
            #pragma unroll
            for (int i = 0; i < 4; ++i)
                #pragma unroll
                for (int j = 0; j < 4; ++j)
                    #pragma unroll
                    for (int rh = 0; rh < 2; ++rh)
                        qbf[(i * 4 + j) * 2 + rh] = pk2(acc1[i][j][2 * rh], acc1[i][j][2 * rh + 1]);
        }

        // ---- g2: P3 = P@Q, 4 column passes, 16-row band per wave ----
        #pragma unroll
        for (int jp = 0; jp < 4; ++jp) {
            if (wc == jp) {   // dump this wave's Q tile as B-panel cols jp*64..+64
                #pragma unroll
                for (int i = 0; i < 4; ++i)
                    #pragma unroll
                    for (int j = 0; j < 4; ++j) {
                        int cl = j * 16 + l15;
                        int k0 = wr * 64 + i * 16 + quad * 4;
                        int addr = cl * 256 + (((k0 >> 3) ^ (cl & 7)) << 3) + (k0 & 7);
                        *(uint2*)(sQ + addr) = make_uint2(qbf[(i * 4 + j) * 2], qbf[(i * 4 + j) * 2 + 1]);
                    }
            }
            __syncthreads();
            f32x4 acc2[4];
            #pragma unroll
            for (int jj = 0; jj < 4; ++jj) acc2[jj] = (f32x4){0.f, 0.f, 0.f, 0.f};
            #pragma unroll
            for (int s = 0; s < 8; ++s) {
                bf16x8 a = ldP(Plds, wave * 16 + l15, s * 4 + quad);
                #pragma unroll
                for (int jj = 0; jj < 4; ++jj) {
                    int cl = jj * 16 + l15;
                    bf16x8 b = *(const bf16x8*)(sQ + cl * 256 + (((s * 4 + quad) ^ (cl & 7)) << 3));
                    acc2[jj] = __builtin_amdgcn_mfma_f32_16x16x32_bf16(a, b, acc2[jj], 0, 0, 0);
                }
            }
            #pragma unroll
            for (int jj = 0; jj < 4; ++jj)
                #pragma unroll
                for (int rh = 0; rh < 2; ++rh)
                    p3bf[(jp * 4 + jj) * 2 + rh] = pk2(acc2[jj][2 * rh], acc2[jj][2 * rh + 1]);
            __syncthreads();
        }

        // ---- g3: P' = 1.5P - 0.5*P3@(Sh+Sl), 2 col passes x 8 k-panels ----
        uint4 greg = *(const uint4*)(sBase + (size_t)cl_st * 256 + gch_st * 8);  // (jc=0,s=0)
        #pragma unroll
        for (int jc = 0; jc < 2; ++jc) {
            f32x4 acc3[8];
            #pragma unroll
            for (int jj = 0; jj < 8; ++jj) acc3[jj] = (f32x4){0.f, 0.f, 0.f, 0.f};
            #pragma unroll
            for (int s = 0; s < 8; ++s) {
                // dump A-panel (k = cols s*32..+32 of P3) from p3bf
                #pragma unroll
                for (int jjh = 0; jjh < 2; ++jjh) {
                    int jjsrc = (s & 1) * 2 + jjh;
                    int kloc = jjh * 16 + l15;
                    int ch = kloc >> 3, k7 = kloc & 7;
                    #pragma unroll
                    for (int rh = 0; rh < 2; ++rh) {
                        u32 wv = p3bf[((s >> 1) * 4 + jjsrc) * 2 + rh];
                        #pragma unroll
                        for (int bit = 0; bit < 2; ++bit) {
                            int row = wave * 16 + quad * 4 + 2 * rh + bit;
                            int sw = (row ^ (row >> 2)) & 3;
                            sA[row * 32 + ((ch ^ sw) << 3) + k7] =
                                (u16)(bit ? (wv >> 16) : (wv & 0xffffu));
                        }
                    }
                }
                // S panel for THIS step (prefetched last step)
                *(uint4*)sDst = greg;
                // prefetch next step's S panel (flies across raw barriers)
                if (!(jc == 1 && s == 7)) {
                    int t = jc * 8 + s + 1;
                    int jcn = t >> 3, sn = t & 7;
                    greg = *(const uint4*)(sBase + (size_t)(jcn * 128 + cl_st) * 256 + sn * 32 + gch_st * 8);
                }
                asm volatile("s_waitcnt lgkmcnt(0)" ::: "memory");
                __builtin_amdgcn_s_barrier();
                // compute
                {
                    int ar = wave * 16 + l15;
                    int asw = (ar ^ (ar >> 2)) & 3;
                    bf16x8 a = *(const bf16x8*)(sA + ar * 32 + ((quad ^ asw) << 3));
                    #pragma unroll
                    for (int jj = 0; jj < 8; ++jj) {
                        int cl = jj * 16 + l15;
                        int co = cl * 32 + ((quad ^ (cl & 3)) << 3);
                        bf16x8 bh = *(const bf16x8*)(sS + co);
                        bf16x8 bl = *(const bf16x8*)(sS + 4096 + co);
                        acc3[jj] = __builtin_amdgcn_mfma_f32_16x16x32_bf16(a, bh, acc3[jj], 0, 0, 0);
                        acc3[jj] = __builtin_amdgcn_mfma_f32_16x16x32_bf16(a, bl, acc3[jj], 0, 0, 0);
                    }
                }
                asm volatile("s_waitcnt lgkmcnt(0)" ::: "memory");
                __builtin_amdgcn_s_barrier();
            }
            // epilogue for this column pass (own cells only -> race-free)
            #pragma unroll
            for (int jj = 0; jj < 8; ++jj)
                #pragma unroll
                for (int r = 0; r < 4; ++r) {
                    int row = wave * 16 + quad * 4 + r;
                    int col = jc * 128 + jj * 16 + l15;
                    int pa = row * 256 + (((col >> 3) ^ (row & 7)) << 3) + (col & 7);
                    float pv = 1.5f * b2f(Plds[pa]) - 0.5f * acc3[jj][r];
                    if (last) Wg[(size_t)n * 65536 + row * 256 + col] = f2b(pv * rtr);
                    else Plds[pa] = f2b(pv);
                }
        }
        __syncthreads();   // new P fully written before next iteration's g1
    }
}

// ---------------------------------------------------------------------------
// Kernel 5: out = Xn @ W (W symmetric bf16, stride 65536). fp32 out.
// ---------------------------------------------------------------------------
__global__ __launch_bounds__(256) void final_gemm(const u16* __restrict__ xn,
                                                  const u16* __restrict__ Wh,
                                                  float* __restrict__ out) {
    __shared__ u16 sA[128 * 32];
    __shared__ u16 sB[128 * 32];
    const int bid = blockIdx.x;
    const int xcd = bid & 7, slot = bid >> 3;
    const int t = slot & 7;
    const int n = ((slot >> 3) << 3) | xcd;
    const int tr = t >> 1, tc = t & 1;
    const int tid = threadIdx.x;
    const int lane = tid & 63, wave = tid >> 6;
    const int wr = wave >> 1, wc = wave & 1;
    const int l15 = lane & 15, quad = lane >> 4;
    const int row0 = tid >> 2, q = tid & 3;
    const int wb8 = (tid & 192) * 8;

    const u16* gA = xn + (size_t)n * Mm * Dd + (size_t)(tr * 128) * Dd;
    const u16* gB = Wh + (size_t)n * Dd * Dd + (size_t)(tc * 128) * Dd;

    f32x4 acc[4][4];
    #pragma unroll
    for (int i = 0; i < 4; ++i)
        #pragma unroll
        for (int j = 0; j < 4; ++j) acc[i][j] = (f32x4){0.f, 0.f, 0.f, 0.f};

    for (int kk = 0; kk < Dd; kk += 32) {
        glds16(gA + (size_t)row0 * Dd + kk + q * 8, sA + wb8);
        glds16(gA + (size_t)(row0 + 64) * Dd + kk + q * 8, sA + 2048 + wb8);
        glds16(gB + (size_t)row0 * Dd + kk + q * 8, sB + wb8);
        glds16(gB + (size_t)(row0 + 64) * Dd + kk + q * 8, sB + 2048 + wb8);
        __syncthreads();
        bf16x8 a[4], b[4];
        #pragma unroll
        for (int i = 0; i < 4; ++i) a[i] = *(const bf16x8*)(sA + (wr * 64 + i * 16 + l15) * 32 + quad * 8);
        #pragma unroll
        for (int j = 0; j < 4; ++j) b[j] = *(const bf16x8*)(sB + (wc * 64 + j * 16 + l15) * 32 + quad * 8);
        #pragma unroll
        for (int i = 0; i < 4; ++i)
            #pragma unroll
            for (int j = 0; j < 4; ++j)
                acc[i][j] = __builtin_amdgcn_mfma_f32_16x16x32_bf16(a[i], b[j], acc[i][j], 0, 0, 0);
        __syncthreads();
    }

    float* ob = out + (size_t)n * Mm * Dd;
    #pragma unroll
    for (int i = 0; i < 4; ++i)
        #pragma unroll
        for (int j = 0; j < 4; ++j)
            #pragma unroll
            for (int r = 0; r < 4; ++r) {
                int row = tr * 128 + wr * 64 + i * 16 + quad * 4 + r;
                int col = tc * 128 + wc * 64 + j * 16 + l15;
                ob[(size_t)row * Dd + col] = acc[i][j][r];
            }
}

// ---------------------------------------------------------------------------
// Workspace (32MB units):
//  u0-1 xn | u2-3 xnT (dead after sigma) -> W at u2 (32MB)
//  u4-5 sigma fp32 | u6 Sh | u7 Sl | u9 meanPart
// ---------------------------------------------------------------------------
extern "C" void kernel_launch(void* const* d_in, const int* in_sizes, int n_in,
                              void* d_out, int out_size, void* d_ws, size_t ws_size,
                              hipStream_t stream) {
    const float* x = (const float*)d_in[0];
    float* out = (float*)d_out;
    char* ws = (char*)d_ws;
    const size_t MB32 = 33554432;

    u16* xn = (u16*)(ws + 0);
    u16* xnT = (u16*)(ws + 2 * MB32);
    u16* W = (u16*)(ws + 2 * MB32);    // alias xnT (dead after sigma)
    float* sigma = (float*)(ws + 4 * MB32);
    u16* Sh = (u16*)(ws + 6 * MB32);
    u16* Sl = (u16*)(ws + 7 * MB32);
    float* meanPart = (float*)(ws + 9 * MB32);

    mean_part_kernel<<<Nn * 4, 256, 0, stream>>>(x, meanPart);
    center_tr_kernel<<<Nn * 8, 256, 0, stream>>>(x, meanPart, xn, xnT);
    sigma_kernel<<<Nn * 4, 256, 0, stream>>>(xnT, sigma);
    ns_chain_kernel<<<Nn, 1024, 0, stream>>>(sigma, W, Sh, Sl);
    final_gemm<<<Nn * 8, 256, 0, stream>>>(xn, W, out);
}

// Round 4
// 700.014 us; speedup vs baseline: 1.4844x; 1.0352x over previous
//
#include <hip/hip_runtime.h>
#include <stdint.h>

#define Nn 256
#define Mm 512
#define Dd 256

typedef unsigned short u16;
typedef unsigned int u32;
typedef __attribute__((ext_vector_type(8))) short bf16x8;
typedef __attribute__((ext_vector_type(4))) float f32x4;

__device__ __forceinline__ u16 f2b(float f) {
    unsigned u = __float_as_uint(f);
    return (u16)((u + 0x7FFFu + ((u >> 16) & 1u)) >> 16);  // RNE to bf16
}
__device__ __forceinline__ float b2f(u16 h) {
    return __uint_as_float(((unsigned)h) << 16);
}
__device__ __forceinline__ u32 pk2(float lo, float hi) {
    return (u32)f2b(lo) | ((u32)f2b(hi) << 16);
}
__device__ __forceinline__ void glds16(const u16* g, u16* l) {
    __builtin_amdgcn_global_load_lds((const __attribute__((address_space(1))) void*)g,
                                     (__attribute__((address_space(3))) void*)l, 16, 0, 0);
}

// ---------------------------------------------------------------------------
// Kernel 1a: partial column sums. grid = Nn*4; block (n, c) sums 128 rows.
// ---------------------------------------------------------------------------
__global__ __launch_bounds__(256) void mean_part_kernel(const float* __restrict__ x,
                                                        float* __restrict__ meanPart) {
    const int bid = blockIdx.x;
    const int n = bid >> 2, c = bid & 3;
    const int tid = threadIdx.x;
    const float* xb = x + (size_t)n * Mm * Dd + (size_t)c * 128 * Dd;
    float a0 = 0.f, a1 = 0.f, a2 = 0.f, a3 = 0.f;
    for (int m = 0; m < 128; m += 4) {
        a0 += xb[(m + 0) * Dd + tid];
        a1 += xb[(m + 1) * Dd + tid];
        a2 += xb[(m + 2) * Dd + tid];
        a3 += xb[(m + 3) * Dd + tid];
    }
    meanPart[((size_t)n * 4 + c) * Dd + tid] = a0 + a1 + a2 + a3;
}

// ---------------------------------------------------------------------------
// Kernel 1b: center + emit xn bf16 [n][m][d] and xnT bf16 [n][d][m].
// ---------------------------------------------------------------------------
__global__ __launch_bounds__(256) void center_tr_kernel(const float* __restrict__ x,
                                                        const float* __restrict__ meanPart,
                                                        u16* __restrict__ xn,
                                                        u16* __restrict__ xnT) {
    __shared__ float meanS[Dd];
    __shared__ u16 tileS[64 * 66];
    const int bid = blockIdx.x;
    const int n = bid >> 3, mt = bid & 7;
    const int tid = threadIdx.x;

    const float* mp = meanPart + (size_t)n * 4 * Dd;
    meanS[tid] = (mp[tid] + mp[Dd + tid] + mp[2 * Dd + tid] + mp[3 * Dd + tid]) * (1.0f / Mm);
    __syncthreads();

    const float* xb = x + (size_t)n * Mm * Dd;
    u16* xnb = xn + (size_t)n * Mm * Dd;
    u16* xtb = xnT + (size_t)n * Dd * Mm;
    const int mrow = tid >> 4, dq = tid & 15;
    const int tx2 = (tid & 31) * 2, ty = tid >> 5;

    for (int dt = 0; dt < Dd / 64; ++dt) {
        #pragma unroll
        for (int rr = 0; rr < 4; ++rr) {
            int ml = mrow + 16 * rr;
            int m = mt * 64 + ml;
            int d = dt * 64 + dq * 4;
            float4 v = *(const float4*)(xb + (size_t)m * Dd + d);
            float4 mu = *(const float4*)(meanS + d);
            u16 b0 = f2b(v.x - mu.x), b1 = f2b(v.y - mu.y);
            u16 b2 = f2b(v.z - mu.z), b3 = f2b(v.w - mu.w);
            u32 lo = (u32)b0 | ((u32)b1 << 16);
            u32 hi = (u32)b2 | ((u32)b3 << 16);
            *(uint2*)(xnb + (size_t)m * Dd + d) = make_uint2(lo, hi);
            tileS[(dq * 4 + 0) * 66 + ml] = b0;
            tileS[(dq * 4 + 1) * 66 + ml] = b1;
            tileS[(dq * 4 + 2) * 66 + ml] = b2;
            tileS[(dq * 4 + 3) * 66 + ml] = b3;
        }
        __syncthreads();
        #pragma unroll
        for (int r = 0; r < 8; ++r) {
            int dl = r * 8 + ty;
            u32 w = *(const u32*)(tileS + dl * 66 + tx2);
            *(u32*)(xtb + (size_t)(dt * 64 + dl) * Mm + mt * 64 + tx2) = w;
        }
        __syncthreads();
    }
}

// ---------------------------------------------------------------------------
// Kernel 2: sigma[n] = XnT @ XnT^T (raw fp32). XCD-swizzled.
// ---------------------------------------------------------------------------
__global__ __launch_bounds__(256) void sigma_kernel(const u16* __restrict__ xnT,
                                                    float* __restrict__ sigma) {
    __shared__ u16 sA[128 * 32];
    __shared__ u16 sB[128 * 32];
    const int bid = blockIdx.x;
    const int xcd = bid & 7, slot = bid >> 3;
    const int t = slot & 3;
    const int n = ((slot >> 2) << 3) | xcd;
    const int tr = t >> 1, tc = t & 1;
    const int tid = threadIdx.x;
    const int lane = tid & 63, wave = tid >> 6;
    const int wr = wave >> 1, wc = wave & 1;
    const int l15 = lane & 15, quad = lane >> 4;
    const int row0 = tid >> 2, q = tid & 3;
    const int wb8 = (tid & 192) * 8;

    const u16* base = xnT + (size_t)n * Dd * Mm;
    const u16* gA = base + (size_t)(tr * 128) * Mm;
    const u16* gB = base + (size_t)(tc * 128) * Mm;

    f32x4 acc[4][4];
    #pragma unroll
    for (int i = 0; i < 4; ++i)
        #pragma unroll
        for (int j = 0; j < 4; ++j) acc[i][j] = (f32x4){0.f, 0.f, 0.f, 0.f};

    for (int kk = 0; kk < Mm; kk += 32) {
        glds16(gA + (size_t)row0 * Mm + kk + q * 8, sA + wb8);
        glds16(gA + (size_t)(row0 + 64) * Mm + kk + q * 8, sA + 2048 + wb8);
        glds16(gB + (size_t)row0 * Mm + kk + q * 8, sB + wb8);
        glds16(gB + (size_t)(row0 + 64) * Mm + kk + q * 8, sB + 2048 + wb8);
        __syncthreads();
        bf16x8 a[4], b[4];
        #pragma unroll
        for (int i = 0; i < 4; ++i) a[i] = *(const bf16x8*)(sA + (wr * 64 + i * 16 + l15) * 32 + quad * 8);
        #pragma unroll
        for (int j = 0; j < 4; ++j) b[j] = *(const bf16x8*)(sB + (wc * 64 + j * 16 + l15) * 32 + quad * 8);
        #pragma unroll
        for (int i = 0; i < 4; ++i)
            #pragma unroll
            for (int j = 0; j < 4; ++j)
                acc[i][j] = __builtin_amdgcn_mfma_f32_16x16x32_bf16(a[i], b[j], acc[i][j], 0, 0, 0);
        __syncthreads();
    }

    float* sg = sigma + (size_t)n * Dd * Dd;
    #pragma unroll
    for (int i = 0; i < 4; ++i)
        #pragma unroll
        for (int j = 0; j < 4; ++j)
            #pragma unroll
            for (int r = 0; r < 4; ++r) {
                int row = tr * 128 + wr * 64 + i * 16 + quad * 4 + r;
                int col = tc * 128 + wc * 64 + j * 16 + l15;
                sg[row * Dd + col] = acc[i][j][r];
            }
}

// ---------------------------------------------------------------------------
// Fused NS chain v4: one block (1024 thr, 16 waves) per batch.
// Same dataflow as v3 (bitwise-identical per-element accumulation order),
// restructured for register pressure:
//   g1: Q = P@P in TWO half-passes (64x32 tiles, acc 32 f32) -> no spill
//   g2: P3 = P@Q unchanged (col-panel strips, 16x64 tiles, acc 16 f32)
//   g3: P' = 1.5P-.5*P3@(Sh+Sl): 32x64 tiles (8x2 wave grid, acc 32 f32,
//       10 LDS reads / 16 MFMAs instead of 17)
// ---------------------------------------------------------------------------
__device__ __forceinline__ bf16x8 ldP(const u16* Plds, int row, int ch) {
    return *(const bf16x8*)(Plds + row * 256 + ((ch ^ (row & 7)) << 3));
}

__global__ __launch_bounds__(1024, 4) void ns_chain_kernel(const float* __restrict__ sigma,
                                                           u16* __restrict__ Wg,
                                                           u16* __restrict__ Sh,
                                                           u16* __restrict__ Sl) {
    __shared__ __align__(16) u16 lds[81920];   // 160 KB
    u16* Plds = lds;
    u16* strips = lds + 65536;   // 16384 u16 = 32KB
    u16* sQ = strips;            // g2: [64][256]
    u16* sA = strips;            // g3: [256][32]
    u16* sS = strips + 8192;     // g3: Sh [128][32] + Sl [128][32]

    const int n = blockIdx.x, tid = threadIdx.x;
    const int lane = tid & 63, wave = tid >> 6;
    const int l15 = lane & 15, quad = lane >> 4;
    const int wr = wave >> 2, wc = wave & 3;      // g1: 4x4 grid of 64x64
    const int wr8 = wave >> 1, wc2 = wave & 1;    // g3: 8x2 grid of 32x64

    const float* sg = sigma + (size_t)n * 65536;
    u16* shp = Sh + (size_t)n * 65536;
    u16* slp = Sl + (size_t)n * 65536;

    // ---- phase 0: trace, split S -> global, P1 -> LDS (swizzled) ----
    float* red = (float*)strips;
    if (tid < 256) red[tid] = sg[tid * 257];
    __syncthreads();
    for (int s = 128; s > 0; s >>= 1) {
        if (tid < s) red[tid] += red[tid + s];
        __syncthreads();
    }
    const float inv = 1.0f / red[0];
    const float rtr = sqrtf(511.0f * inv);

    #pragma unroll 4
    for (int itp = 0; itp < 16; ++itp) {
        int idx = itp * 4096 + tid * 4;
        float4 v = *(const float4*)(sg + idx);
        int row = idx >> 8, col = idx & 255;
        float s0 = v.x * inv, s1 = v.y * inv, s2 = v.z * inv, s3 = v.w * inv;
        u16 h0 = f2b(s0), h1 = f2b(s1), h2 = f2b(s2), h3 = f2b(s3);
        *(uint2*)(shp + idx) = make_uint2((u32)h0 | ((u32)h1 << 16), (u32)h2 | ((u32)h3 << 16));
        u16 e0 = f2b(s0 - b2f(h0)), e1 = f2b(s1 - b2f(h1));
        u16 e2 = f2b(s2 - b2f(h2)), e3 = f2b(s3 - b2f(h3));
        *(uint2*)(slp + idx) = make_uint2((u32)e0 | ((u32)e1 << 16), (u32)e2 | ((u32)e3 << 16));
        u16 p0 = f2b(((row == col + 0) ? 1.5f : 0.f) - 0.5f * s0);
        u16 p1 = f2b(((row == col + 1) ? 1.5f : 0.f) - 0.5f * s1);
        u16 p2 = f2b(((row == col + 2) ? 1.5f : 0.f) - 0.5f * s2);
        u16 p3 = f2b(((row == col + 3) ? 1.5f : 0.f) - 0.5f * s3);
        int pa = row * 256 + (((col >> 3) ^ (row & 7)) << 3) + (col & 7);
        *(uint2*)(Plds + pa) = make_uint2((u32)p0 | ((u32)p1 << 16), (u32)p2 | ((u32)p3 << 16));
    }
    __syncthreads();   // full drain: S stores visible before any re-read

    // S-staging per-lane constants: waves 0-7 stage Sh, 8-15 stage Sl.
    const u16* sBase = (wave < 8) ? shp : slp;
    const int w8 = wave & 7;
    const int cl_st = w8 * 16 + (lane >> 2);        // strip row (= S column)
    const int gch_st = (lane & 3) ^ (cl_st & 3);    // pre-swizzled src chunk
    u16* sDst = sS + ((wave < 8) ? 0 : 4096) + w8 * 512 + lane * 8;

    // ---- 3 NS iterations ----
    #pragma unroll 1
    for (int it = 0; it < 3; ++it) {
        const bool last = (it == 2);
        u32 qbf[32], p3bf[32];

        // ---- g1: Q = P@P, two half-passes (64x32 tiles, acc 32 f32) ----
        #pragma unroll
        for (int h = 0; h < 2; ++h) {
            f32x4 acc1[4][2];
            #pragma unroll
            for (int i = 0; i < 4; ++i)
                #pragma unroll
                for (int jj = 0; jj < 2; ++jj) acc1[i][jj] = (f32x4){0.f, 0.f, 0.f, 0.f};
            #pragma unroll
            for (int s = 0; s < 8; ++s) {
                bf16x8 a[4], b[2];
                #pragma unroll
                for (int i = 0; i < 4; ++i) a[i] = ldP(Plds, wr * 64 + i * 16 + l15, s * 4 + quad);
                #pragma unroll
                for (int jj = 0; jj < 2; ++jj)
                    b[jj] = ldP(Plds, wc * 64 + (2 * h + jj) * 16 + l15, s * 4 + quad);
                #pragma unroll
                for (int i = 0; i < 4; ++i)
                    #pragma unroll
                    for (int jj = 0; jj < 2; ++jj)
                        acc1[i][jj] = __builtin_amdgcn_mfma_f32_16x16x32_bf16(a[i], b[jj], acc1[i][jj], 0, 0, 0);
            }
            #pragma unroll
            for (int i = 0; i < 4; ++i)
                #pragma unroll
                for (int jj = 0; jj < 2; ++jj)
                    #pragma unroll
                    for (int rh = 0; rh < 2; ++rh)
                        qbf[(i * 4 + 2 * h + jj) * 2 + rh] =
                            pk2(acc1[i][jj][2 * rh], acc1[i][jj][2 * rh + 1]);
        }

        // ---- g2: P3 = P@Q, 4 column passes, 16-row band per wave ----
        #pragma unroll
        for (int jp = 0; jp < 4; ++jp) {
            if (wc == jp) {   // dump this wave's Q tile as B-panel cols jp*64..+64
                #pragma unroll
                for (int i = 0; i < 4; ++i)
                    #pragma unroll
                    for (int j = 0; j < 4; ++j) {
                        int cl = j * 16 + l15;
                        int k0 = wr * 64 + i * 16 + quad * 4;
                        int addr = cl * 256 + (((k0 >> 3) ^ (cl & 7)) << 3) + (k0 & 7);
                        *(uint2*)(sQ + addr) = make_uint2(qbf[(i * 4 + j) * 2], qbf[(i * 4 + j) * 2 + 1]);
                    }
            }
            __syncthreads();
            f32x4 acc2[4];
            #pragma unroll
            for (int jj = 0; jj < 4; ++jj) acc2[jj] = (f32x4){0.f, 0.f, 0.f, 0.f};
            #pragma unroll
            for (int s = 0; s < 8; ++s) {
                bf16x8 a = ldP(Plds, wave * 16 + l15, s * 4 + quad);
                #pragma unroll
                for (int jj = 0; jj < 4; ++jj) {
                    int cl = jj * 16 + l15;
                    bf16x8 b = *(const bf16x8*)(sQ + cl * 256 + (((s * 4 + quad) ^ (cl & 7)) << 3));
                    acc2[jj] = __builtin_amdgcn_mfma_f32_16x16x32_bf16(a, b, acc2[jj], 0, 0, 0);
                }
            }
            #pragma unroll
            for (int jj = 0; jj < 4; ++jj)
                #pragma unroll
                for (int rh = 0; rh < 2; ++rh)
                    p3bf[(jp * 4 + jj) * 2 + rh] = pk2(acc2[jj][2 * rh], acc2[jj][2 * rh + 1]);
            __syncthreads();
        }

        // ---- g3: P' = 1.5P - 0.5*P3@(Sh+Sl), 2 col passes, 32x64 tiles ----
        uint4 greg = *(const uint4*)(sBase + (size_t)cl_st * 256 + gch_st * 8);  // (jc=0,s=0)
        #pragma unroll
        for (int jc = 0; jc < 2; ++jc) {
            f32x4 acc3[2][4];
            #pragma unroll
            for (int i16 = 0; i16 < 2; ++i16)
                #pragma unroll
                for (int j = 0; j < 4; ++j) acc3[i16][j] = (f32x4){0.f, 0.f, 0.f, 0.f};
            #pragma unroll
            for (int s = 0; s < 8; ++s) {
                // dump A-panel (k = cols s*32..+32 of P3) from p3bf
                #pragma unroll
                for (int jjh = 0; jjh < 2; ++jjh) {
                    int jjsrc = (s & 1) * 2 + jjh;
                    int kloc = jjh * 16 + l15;
                    int ch = kloc >> 3, k7 = kloc & 7;
                    #pragma unroll
                    for (int rh = 0; rh < 2; ++rh) {
                        u32 wv = p3bf[((s >> 1) * 4 + jjsrc) * 2 + rh];
                        #pragma unroll
                        for (int bit = 0; bit < 2; ++bit) {
                            int row = wave * 16 + quad * 4 + 2 * rh + bit;
                            int sw = (row ^ (row >> 2)) & 3;
                            sA[row * 32 + ((ch ^ sw) << 3) + k7] =
                                (u16)(bit ? (wv >> 16) : (wv & 0xffffu));
                        }
                    }
                }
                // S panel for THIS step (prefetched last step)
                *(uint4*)sDst = greg;
                // prefetch next step's S panel (flies across raw barriers)
                if (!(jc == 1 && s == 7)) {
                    int t = jc * 8 + s + 1;
                    int jcn = t >> 3, sn = t & 7;
                    greg = *(const uint4*)(sBase + (size_t)(jcn * 128 + cl_st) * 256 + sn * 32 + gch_st * 8);
                }
                asm volatile("s_waitcnt lgkmcnt(0)" ::: "memory");
                __builtin_amdgcn_s_barrier();
                // compute: 32x64 tile per wave (rows wr8*32.., cols jc*128+wc2*64..)
                {
                    bf16x8 a[2];
                    #pragma unroll
                    for (int i16 = 0; i16 < 2; ++i16) {
                        int ar = wr8 * 32 + i16 * 16 + l15;
                        int asw = (ar ^ (ar >> 2)) & 3;
                        a[i16] = *(const bf16x8*)(sA + ar * 32 + ((quad ^ asw) << 3));
                    }
                    #pragma unroll
                    for (int j = 0; j < 4; ++j) {
                        int cl = wc2 * 64 + j * 16 + l15;
                        int co = cl * 32 + ((quad ^ (cl & 3)) << 3);
                        bf16x8 bh = *(const bf16x8*)(sS + co);
                        bf16x8 bl = *(const bf16x8*)(sS + 4096 + co);
                        #pragma unroll
                        for (int i16 = 0; i16 < 2; ++i16)
                            acc3[i16][j] = __builtin_amdgcn_mfma_f32_16x16x32_bf16(a[i16], bh, acc3[i16][j], 0, 0, 0);
                        #pragma unroll
                        for (int i16 = 0; i16 < 2; ++i16)
                            acc3[i16][j] = __builtin_amdgcn_mfma_f32_16x16x32_bf16(a[i16], bl, acc3[i16][j], 0, 0, 0);
                    }
                }
                asm volatile("s_waitcnt lgkmcnt(0)" ::: "memory");
                __builtin_amdgcn_s_barrier();
            }
            // epilogue for this column pass (own cells only -> race-free)
            #pragma unroll
            for (int i16 = 0; i16 < 2; ++i16)
                #pragma unroll
                for (int j = 0; j < 4; ++j)
                    #pragma unroll
                    for (int r = 0; r < 4; ++r) {
                        int row = wr8 * 32 + i16 * 16 + quad * 4 + r;
                        int col = jc * 128 + wc2 * 64 + j * 16 + l15;
                        int pa = row * 256 + (((col >> 3) ^ (row & 7)) << 3) + (col & 7);
                        float pv = 1.5f * b2f(Plds[pa]) - 0.5f * acc3[i16][j][r];
                        if (last) Wg[(size_t)n * 65536 + row * 256 + col] = f2b(pv * rtr);
                        else Plds[pa] = f2b(pv);
                    }
        }
        __syncthreads();   // new P fully written before next iteration's g1
    }
}

// ---------------------------------------------------------------------------
// Kernel 5: out = Xn @ W (W symmetric bf16, stride 65536). fp32 out.
// ---------------------------------------------------------------------------
__global__ __launch_bounds__(256) void final_gemm(const u16* __restrict__ xn,
                                                  const u16* __restrict__ Wh,
                                                  float* __restrict__ out) {
    __shared__ u16 sA[128 * 32];
    __shared__ u16 sB[128 * 32];
    const int bid = blockIdx.x;
    const int xcd = bid & 7, slot = bid >> 3;
    const int t = slot & 7;
    const int n = ((slot >> 3) << 3) | xcd;
    const int tr = t >> 1, tc = t & 1;
    const int tid = threadIdx.x;
    const int lane = tid & 63, wave = tid >> 6;
    const int wr = wave >> 1, wc = wave & 1;
    const int l15 = lane & 15, quad = lane >> 4;
    const int row0 = tid >> 2, q = tid & 3;
    const int wb8 = (tid & 192) * 8;

    const u16* gA = xn + (size_t)n * Mm * Dd + (size_t)(tr * 128) * Dd;
    const u16* gB = Wh + (size_t)n * Dd * Dd + (size_t)(tc * 128) * Dd;

    f32x4 acc[4][4];
    #pragma unroll
    for (int i = 0; i < 4; ++i)
        #pragma unroll
        for (int j = 0; j < 4; ++j) acc[i][j] = (f32x4){0.f, 0.f, 0.f, 0.f};

    for (int kk = 0; kk < Dd; kk += 32) {
        glds16(gA + (size_t)row0 * Dd + kk + q * 8, sA + wb8);
        glds16(gA + (size_t)(row0 + 64) * Dd + kk + q * 8, sA + 2048 + wb8);
        glds16(gB + (size_t)row0 * Dd + kk + q * 8, sB + wb8);
        glds16(gB + (size_t)(row0 + 64) * Dd + kk + q * 8, sB + 2048 + wb8);
        __syncthreads();
        bf16x8 a[4], b[4];
        #pragma unroll
        for (int i = 0; i < 4; ++i) a[i] = *(const bf16x8*)(sA + (wr * 64 + i * 16 + l15) * 32 + quad * 8);
        #pragma unroll
        for (int j = 0; j < 4; ++j) b[j] = *(const bf16x8*)(sB + (wc * 64 + j * 16 + l15) * 32 + quad * 8);
        #pragma unroll
        for (int i = 0; i < 4; ++i)
            #pragma unroll
            for (int j = 0; j < 4; ++j)
                acc[i][j] = __builtin_amdgcn_mfma_f32_16x16x32_bf16(a[i], b[j], acc[i][j], 0, 0, 0);
        __syncthreads();
    }

    float* ob = out + (size_t)n * Mm * Dd;
    #pragma unroll
    for (int i = 0; i < 4; ++i)
        #pragma unroll
        for (int j = 0; j < 4; ++j)
            #pragma unroll
            for (int r = 0; r < 4; ++r) {
                int row = tr * 128 + wr * 64 + i * 16 + quad * 4 + r;
                int col = tc * 128 + wc * 64 + j * 16 + l15;
                ob[(size_t)row * Dd + col] = acc[i][j][r];
            }
}

// ---------------------------------------------------------------------------
// Workspace (32MB units):
//  u0-1 xn | u2-3 xnT (dead after sigma) -> W at u2 (32MB)
//  u4-5 sigma fp32 | u6 Sh | u7 Sl | u9 meanPart
// ---------------------------------------------------------------------------
extern "C" void kernel_launch(void* const* d_in, const int* in_sizes, int n_in,
                              void* d_out, int out_size, void* d_ws, size_t ws_size,
                              hipStream_t stream) {
    const float* x = (const float*)d_in[0];
    float* out = (float*)d_out;
    char* ws = (char*)d_ws;
    const size_t MB32 = 33554432;

    u16* xn = (u16*)(ws + 0);
    u16* xnT = (u16*)(ws + 2 * MB32);
    u16* W = (u16*)(ws + 2 * MB32);    // alias xnT (dead after sigma)
    float* sigma = (float*)(ws + 4 * MB32);
    u16* Sh = (u16*)(ws + 6 * MB32);
    u16* Sl = (u16*)(ws + 7 * MB32);
    float* meanPart = (float*)(ws + 9 * MB32);

    mean_part_kernel<<<Nn * 4, 256, 0, stream>>>(x, meanPart);
    center_tr_kernel<<<Nn * 8, 256, 0, stream>>>(x, meanPart, xn, xnT);
    sigma_kernel<<<Nn * 4, 256, 0, stream>>>(xnT, sigma);
    ns_chain_kernel<<<Nn, 1024, 0, stream>>>(sigma, W, Sh, Sl);
    final_gemm<<<Nn * 8, 256, 0, stream>>>(xn, W, out);
}

// Round 5
// 626.658 us; speedup vs baseline: 1.6582x; 1.1171x over previous
//
#include <hip/hip_runtime.h>
#include <stdint.h>

#define Nn 256
#define Mm 512
#define Dd 256

typedef unsigned short u16;
typedef unsigned int u32;
typedef __attribute__((ext_vector_type(8))) short bf16x8;
typedef __attribute__((ext_vector_type(4))) float f32x4;

// manual AGPR stash (gfx950: v_accvgpr_read/write, ISA section 10)
#define AGPR_W(dst, src) asm volatile("v_accvgpr_write_b32 %0, %1" : "=a"(dst) : "v"(src))
#define AGPR_R(dst, src) asm volatile("v_accvgpr_read_b32 %0, %1" : "=v"(dst) : "a"(src))

__device__ __forceinline__ u16 f2b(float f) {
    unsigned u = __float_as_uint(f);
    return (u16)((u + 0x7FFFu + ((u >> 16) & 1u)) >> 16);  // RNE to bf16
}
__device__ __forceinline__ float b2f(u16 h) {
    return __uint_as_float(((unsigned)h) << 16);
}
__device__ __forceinline__ u32 pk2(float lo, float hi) {
    return (u32)f2b(lo) | ((u32)f2b(hi) << 16);
}
__device__ __forceinline__ void glds16(const u16* g, u16* l) {
    __builtin_amdgcn_global_load_lds((const __attribute__((address_space(1))) void*)g,
                                     (__attribute__((address_space(3))) void*)l, 16, 0, 0);
}

// ---------------------------------------------------------------------------
// Kernel 1a: partial column sums. grid = Nn*4; block (n, c) sums 128 rows.
// ---------------------------------------------------------------------------
__global__ __launch_bounds__(256) void mean_part_kernel(const float* __restrict__ x,
                                                        float* __restrict__ meanPart) {
    const int bid = blockIdx.x;
    const int n = bid >> 2, c = bid & 3;
    const int tid = threadIdx.x;
    const float* xb = x + (size_t)n * Mm * Dd + (size_t)c * 128 * Dd;
    float a0 = 0.f, a1 = 0.f, a2 = 0.f, a3 = 0.f;
    for (int m = 0; m < 128; m += 4) {
        a0 += xb[(m + 0) * Dd + tid];
        a1 += xb[(m + 1) * Dd + tid];
        a2 += xb[(m + 2) * Dd + tid];
        a3 += xb[(m + 3) * Dd + tid];
    }
    meanPart[((size_t)n * 4 + c) * Dd + tid] = a0 + a1 + a2 + a3;
}

// ---------------------------------------------------------------------------
// Kernel 1b: center + emit xn bf16 [n][m][d] and xnT bf16 [n][d][m].
// ---------------------------------------------------------------------------
__global__ __launch_bounds__(256) void center_tr_kernel(const float* __restrict__ x,
                                                        const float* __restrict__ meanPart,
                                                        u16* __restrict__ xn,
                                                        u16* __restrict__ xnT) {
    __shared__ float meanS[Dd];
    __shared__ u16 tileS[64 * 66];
    const int bid = blockIdx.x;
    const int n = bid >> 3, mt = bid & 7;
    const int tid = threadIdx.x;

    const float* mp = meanPart + (size_t)n * 4 * Dd;
    meanS[tid] = (mp[tid] + mp[Dd + tid] + mp[2 * Dd + tid] + mp[3 * Dd + tid]) * (1.0f / Mm);
    __syncthreads();

    const float* xb = x + (size_t)n * Mm * Dd;
    u16* xnb = xn + (size_t)n * Mm * Dd;
    u16* xtb = xnT + (size_t)n * Dd * Mm;
    const int mrow = tid >> 4, dq = tid & 15;
    const int tx2 = (tid & 31) * 2, ty = tid >> 5;

    for (int dt = 0; dt < Dd / 64; ++dt) {
        #pragma unroll
        for (int rr = 0; rr < 4; ++rr) {
            int ml = mrow + 16 * rr;
            int m = mt * 64 + ml;
            int d = dt * 64 + dq * 4;
            float4 v = *(const float4*)(xb + (size_t)m * Dd + d);
            float4 mu = *(const float4*)(meanS + d);
            u16 b0 = f2b(v.x - mu.x), b1 = f2b(v.y - mu.y);
            u16 b2 = f2b(v.z - mu.z), b3 = f2b(v.w - mu.w);
            u32 lo = (u32)b0 | ((u32)b1 << 16);
            u32 hi = (u32)b2 | ((u32)b3 << 16);
            *(uint2*)(xnb + (size_t)m * Dd + d) = make_uint2(lo, hi);
            tileS[(dq * 4 + 0) * 66 + ml] = b0;
            tileS[(dq * 4 + 1) * 66 + ml] = b1;
            tileS[(dq * 4 + 2) * 66 + ml] = b2;
            tileS[(dq * 4 + 3) * 66 + ml] = b3;
        }
        __syncthreads();
        #pragma unroll
        for (int r = 0; r < 8; ++r) {
            int dl = r * 8 + ty;
            u32 w = *(const u32*)(tileS + dl * 66 + tx2);
            *(u32*)(xtb + (size_t)(dt * 64 + dl) * Mm + mt * 64 + tx2) = w;
        }
        __syncthreads();
    }
}

// ---------------------------------------------------------------------------
// Kernel 2: sigma[n] = XnT @ XnT^T (raw fp32). XCD-swizzled.
// ---------------------------------------------------------------------------
__global__ __launch_bounds__(256) void sigma_kernel(const u16* __restrict__ xnT,
                                                    float* __restrict__ sigma) {
    __shared__ u16 sA[128 * 32];
    __shared__ u16 sB[128 * 32];
    const int bid = blockIdx.x;
    const int xcd = bid & 7, slot = bid >> 3;
    const int t = slot & 3;
    const int n = ((slot >> 2) << 3) | xcd;
    const int tr = t >> 1, tc = t & 1;
    const int tid = threadIdx.x;
    const int lane = tid & 63, wave = tid >> 6;
    const int wr = wave >> 1, wc = wave & 1;
    const int l15 = lane & 15, quad = lane >> 4;
    const int row0 = tid >> 2, q = tid & 3;
    const int wb8 = (tid & 192) * 8;

    const u16* base = xnT + (size_t)n * Dd * Mm;
    const u16* gA = base + (size_t)(tr * 128) * Mm;
    const u16* gB = base + (size_t)(tc * 128) * Mm;

    f32x4 acc[4][4];
    #pragma unroll
    for (int i = 0; i < 4; ++i)
        #pragma unroll
        for (int j = 0; j < 4; ++j) acc[i][j] = (f32x4){0.f, 0.f, 0.f, 0.f};

    for (int kk = 0; kk < Mm; kk += 32) {
        glds16(gA + (size_t)row0 * Mm + kk + q * 8, sA + wb8);
        glds16(gA + (size_t)(row0 + 64) * Mm + kk + q * 8, sA + 2048 + wb8);
        glds16(gB + (size_t)row0 * Mm + kk + q * 8, sB + wb8);
        glds16(gB + (size_t)(row0 + 64) * Mm + kk + q * 8, sB + 2048 + wb8);
        __syncthreads();
        bf16x8 a[4], b[4];
        #pragma unroll
        for (int i = 0; i < 4; ++i) a[i] = *(const bf16x8*)(sA + (wr * 64 + i * 16 + l15) * 32 + quad * 8);
        #pragma unroll
        for (int j = 0; j < 4; ++j) b[j] = *(const bf16x8*)(sB + (wc * 64 + j * 16 + l15) * 32 + quad * 8);
        #pragma unroll
        for (int i = 0; i < 4; ++i)
            #pragma unroll
            for (int j = 0; j < 4; ++j)
                acc[i][j] = __builtin_amdgcn_mfma_f32_16x16x32_bf16(a[i], b[j], acc[i][j], 0, 0, 0);
        __syncthreads();
    }

    float* sg = sigma + (size_t)n * Dd * Dd;
    #pragma unroll
    for (int i = 0; i < 4; ++i)
        #pragma unroll
        for (int j = 0; j < 4; ++j)
            #pragma unroll
            for (int r = 0; r < 4; ++r) {
                int row = tr * 128 + wr * 64 + i * 16 + quad * 4 + r;
                int col = tc * 128 + wc * 64 + j * 16 + l15;
                sg[row * Dd + col] = acc[i][j][r];
            }
}

// ---------------------------------------------------------------------------
// Fused NS chain v5: same dataflow as v4 (bitwise-identical accumulation
// order), but P3 lives in manually-stashed AGPRs (v_accvgpr_write/read)
// so the arch-VGPR side (64) only holds qbf + frags -> no scratch spill.
//   g1: Q = P@P, two half-passes; frag loads restructured (a inside i-loop)
//   g2: P3 = P@Q, 4 col passes; results stashed straight to AGPR
//   g3: P' = 1.5P-.5*P3@(Sh+Sl), jc loop NOT unrolled (acc3 32 max live)
// ---------------------------------------------------------------------------
__device__ __forceinline__ bf16x8 ldP(const u16* Plds, int row, int ch) {
    return *(const bf16x8*)(Plds + row * 256 + ((ch ^ (row & 7)) << 3));
}

__global__ __launch_bounds__(1024, 4) void ns_chain_kernel(const float* __restrict__ sigma,
                                                           u16* __restrict__ Wg,
                                                           u16* __restrict__ Sh,
                                                           u16* __restrict__ Sl) {
    __shared__ __align__(16) u16 lds[81920];   // 160 KB
    u16* Plds = lds;
    u16* strips = lds + 65536;   // 16384 u16 = 32KB
    u16* sQ = strips;            // g2: [64][256]
    u16* sA = strips;            // g3: [256][32]
    u16* sS = strips + 8192;     // g3: Sh [128][32] + Sl [128][32]

    const int n = blockIdx.x, tid = threadIdx.x;
    const int lane = tid & 63, wave = tid >> 6;
    const int l15 = lane & 15, quad = lane >> 4;
    const int wr = wave >> 2, wc = wave & 3;      // g1/g2: 4x4 grid
    const int wr8 = wave >> 1, wc2 = wave & 1;    // g3: 8x2 grid of 32x64

    const float* sg = sigma + (size_t)n * 65536;
    u16* shp = Sh + (size_t)n * 65536;
    u16* slp = Sl + (size_t)n * 65536;

    // ---- phase 0: trace, split S -> global, P1 -> LDS (swizzled) ----
    float* red = (float*)strips;
    if (tid < 256) red[tid] = sg[tid * 257];
    __syncthreads();
    for (int s = 128; s > 0; s >>= 1) {
        if (tid < s) red[tid] += red[tid + s];
        __syncthreads();
    }
    const float inv = 1.0f / red[0];
    const float rtr = sqrtf(511.0f * inv);

    #pragma unroll 4
    for (int itp = 0; itp < 16; ++itp) {
        int idx = itp * 4096 + tid * 4;
        float4 v = *(const float4*)(sg + idx);
        int row = idx >> 8, col = idx & 255;
        float s0 = v.x * inv, s1 = v.y * inv, s2 = v.z * inv, s3 = v.w * inv;
        u16 h0 = f2b(s0), h1 = f2b(s1), h2 = f2b(s2), h3 = f2b(s3);
        *(uint2*)(shp + idx) = make_uint2((u32)h0 | ((u32)h1 << 16), (u32)h2 | ((u32)h3 << 16));
        u16 e0 = f2b(s0 - b2f(h0)), e1 = f2b(s1 - b2f(h1));
        u16 e2 = f2b(s2 - b2f(h2)), e3 = f2b(s3 - b2f(h3));
        *(uint2*)(slp + idx) = make_uint2((u32)e0 | ((u32)e1 << 16), (u32)e2 | ((u32)e3 << 16));
        u16 p0 = f2b(((row == col + 0) ? 1.5f : 0.f) - 0.5f * s0);
        u16 p1 = f2b(((row == col + 1) ? 1.5f : 0.f) - 0.5f * s1);
        u16 p2 = f2b(((row == col + 2) ? 1.5f : 0.f) - 0.5f * s2);
        u16 p3 = f2b(((row == col + 3) ? 1.5f : 0.f) - 0.5f * s3);
        int pa = row * 256 + (((col >> 3) ^ (row & 7)) << 3) + (col & 7);
        *(uint2*)(Plds + pa) = make_uint2((u32)p0 | ((u32)p1 << 16), (u32)p2 | ((u32)p3 << 16));
    }
    __syncthreads();   // full drain: S stores visible before any re-read

    // S-staging per-lane constants: waves 0-7 stage Sh, 8-15 stage Sl.
    const u16* sBase = (wave < 8) ? shp : slp;
    const int w8 = wave & 7;
    const int cl_st = w8 * 16 + (lane >> 2);        // strip row (= S column)
    const int gch_st = (lane & 3) ^ (cl_st & 3);    // pre-swizzled src chunk
    u16* sDst = sS + ((wave < 8) ? 0 : 4096) + w8 * 512 + lane * 8;

    // ---- 3 NS iterations ----
    #pragma unroll 1
    for (int it = 0; it < 3; ++it) {
        const bool last = (it == 2);
        u32 qbf[32];    // arch VGPRs (dead by end of g2)
        u32 p3a[32];    // AGPR-stashed via v_accvgpr_* (read in g3)

        // ---- g1: Q = P@P, two half-passes (64x32 tiles, acc 32 f32) ----
        #pragma unroll
        for (int h = 0; h < 2; ++h) {
            f32x4 acc1[4][2];
            #pragma unroll
            for (int i = 0; i < 4; ++i)
                #pragma unroll
                for (int jj = 0; jj < 2; ++jj) acc1[i][jj] = (f32x4){0.f, 0.f, 0.f, 0.f};
            #pragma unroll
            for (int s = 0; s < 8; ++s) {
                bf16x8 b0 = ldP(Plds, wc * 64 + (2 * h + 0) * 16 + l15, s * 4 + quad);
                bf16x8 b1 = ldP(Plds, wc * 64 + (2 * h + 1) * 16 + l15, s * 4 + quad);
                #pragma unroll
                for (int i = 0; i < 4; ++i) {
                    bf16x8 a = ldP(Plds, wr * 64 + i * 16 + l15, s * 4 + quad);
                    acc1[i][0] = __builtin_amdgcn_mfma_f32_16x16x32_bf16(a, b0, acc1[i][0], 0, 0, 0);
                    acc1[i][1] = __builtin_amdgcn_mfma_f32_16x16x32_bf16(a, b1, acc1[i][1], 0, 0, 0);
                }
            }
            #pragma unroll
            for (int i = 0; i < 4; ++i)
                #pragma unroll
                for (int jj = 0; jj < 2; ++jj)
                    #pragma unroll
                    for (int rh = 0; rh < 2; ++rh)
                        qbf[(i * 4 + 2 * h + jj) * 2 + rh] =
                            pk2(acc1[i][jj][2 * rh], acc1[i][jj][2 * rh + 1]);
        }

        // ---- g2: P3 = P@Q, 4 column passes, 16-row band per wave ----
        #pragma unroll
        for (int jp = 0; jp < 4; ++jp) {
            if (wc == jp) {   // dump this wave's Q tile as B-panel cols jp*64..+64
                #pragma unroll
                for (int i = 0; i < 4; ++i)
                    #pragma unroll
                    for (int j = 0; j < 4; ++j) {
                        int cl = j * 16 + l15;
                        int k0 = wr * 64 + i * 16 + quad * 4;
                        int addr = cl * 256 + (((k0 >> 3) ^ (cl & 7)) << 3) + (k0 & 7);
                        *(uint2*)(sQ + addr) = make_uint2(qbf[(i * 4 + j) * 2], qbf[(i * 4 + j) * 2 + 1]);
                    }
            }
            __syncthreads();
            f32x4 acc2[4];
            #pragma unroll
            for (int jj = 0; jj < 4; ++jj) acc2[jj] = (f32x4){0.f, 0.f, 0.f, 0.f};
            #pragma unroll
            for (int s = 0; s < 8; ++s) {
                bf16x8 a = ldP(Plds, wave * 16 + l15, s * 4 + quad);
                #pragma unroll
                for (int jj = 0; jj < 4; ++jj) {
                    int cl = jj * 16 + l15;
                    bf16x8 b = *(const bf16x8*)(sQ + cl * 256 + (((s * 4 + quad) ^ (cl & 7)) << 3));
                    acc2[jj] = __builtin_amdgcn_mfma_f32_16x16x32_bf16(a, b, acc2[jj], 0, 0, 0);
                }
            }
            #pragma unroll
            for (int jj = 0; jj < 4; ++jj)
                #pragma unroll
                for (int rh = 0; rh < 2; ++rh)
                    AGPR_W(p3a[(jp * 4 + jj) * 2 + rh], pk2(acc2[jj][2 * rh], acc2[jj][2 * rh + 1]));
            __syncthreads();
        }

        // ---- g3: P' = 1.5P - 0.5*P3@(Sh+Sl), 2 col passes, 32x64 tiles ----
        uint4 greg = *(const uint4*)(sBase + (size_t)cl_st * 256 + gch_st * 8);  // (jc=0,s=0)
        #pragma unroll 1
        for (int jc = 0; jc < 2; ++jc) {
            f32x4 acc3[2][4];
            #pragma unroll
            for (int i16 = 0; i16 < 2; ++i16)
                #pragma unroll
                for (int j = 0; j < 4; ++j) acc3[i16][j] = (f32x4){0.f, 0.f, 0.f, 0.f};
            #pragma unroll
            for (int s = 0; s < 8; ++s) {
                // dump A-panel (k = cols s*32..+32 of P3) from AGPR stash
                #pragma unroll
                for (int jjh = 0; jjh < 2; ++jjh) {
                    int jjsrc = (s & 1) * 2 + jjh;
                    int kloc = jjh * 16 + l15;
                    int ch = kloc >> 3, k7 = kloc & 7;
                    #pragma unroll
                    for (int rh = 0; rh < 2; ++rh) {
                        u32 wv;
                        AGPR_R(wv, p3a[((s >> 1) * 4 + jjsrc) * 2 + rh]);
                        #pragma unroll
                        for (int bit = 0; bit < 2; ++bit) {
                            int row = wave * 16 + quad * 4 + 2 * rh + bit;
                            int sw = (row ^ (row >> 2)) & 3;
                            sA[row * 32 + ((ch ^ sw) << 3) + k7] =
                                (u16)(bit ? (wv >> 16) : (wv & 0xffffu));
                        }
                    }
                }
                // S panel for THIS step (prefetched last step)
                *(uint4*)sDst = greg;
                // prefetch next step's S panel (flies across raw barriers)
                if (!(jc == 1 && s == 7)) {
                    int t = jc * 8 + s + 1;
                    int jcn = t >> 3, sn = t & 7;
                    greg = *(const uint4*)(sBase + (size_t)(jcn * 128 + cl_st) * 256 + sn * 32 + gch_st * 8);
                }
                asm volatile("s_waitcnt lgkmcnt(0)" ::: "memory");
                __builtin_amdgcn_s_barrier();
                // compute: 32x64 tile per wave (rows wr8*32.., cols jc*128+wc2*64..)
                {
                    bf16x8 a[2];
                    #pragma unroll
                    for (int i16 = 0; i16 < 2; ++i16) {
                        int ar = wr8 * 32 + i16 * 16 + l15;
                        int asw = (ar ^ (ar >> 2)) & 3;
                        a[i16] = *(const bf16x8*)(sA + ar * 32 + ((quad ^ asw) << 3));
                    }
                    #pragma unroll
                    for (int j = 0; j < 4; ++j) {
                        int cl = wc2 * 64 + j * 16 + l15;
                        int co = cl * 32 + ((quad ^ (cl & 3)) << 3);
                        bf16x8 bh = *(const bf16x8*)(sS + co);
                        bf16x8 bl = *(const bf16x8*)(sS + 4096 + co);
                        #pragma unroll
                        for (int i16 = 0; i16 < 2; ++i16)
                            acc3[i16][j] = __builtin_amdgcn_mfma_f32_16x16x32_bf16(a[i16], bh, acc3[i16][j], 0, 0, 0);
                        #pragma unroll
                        for (int i16 = 0; i16 < 2; ++i16)
                            acc3[i16][j] = __builtin_amdgcn_mfma_f32_16x16x32_bf16(a[i16], bl, acc3[i16][j], 0, 0, 0);
                    }
                }
                asm volatile("s_waitcnt lgkmcnt(0)" ::: "memory");
                __builtin_amdgcn_s_barrier();
            }
            // epilogue for this column pass (own cells only -> race-free)
            #pragma unroll
            for (int i16 = 0; i16 < 2; ++i16)
                #pragma unroll
                for (int j = 0; j < 4; ++j)
                    #pragma unroll
                    for (int r = 0; r < 4; ++r) {
                        int row = wr8 * 32 + i16 * 16 + quad * 4 + r;
                        int col = jc * 128 + wc2 * 64 + j * 16 + l15;
                        int pa = row * 256 + (((col >> 3) ^ (row & 7)) << 3) + (col & 7);
                        float pv = 1.5f * b2f(Plds[pa]) - 0.5f * acc3[i16][j][r];
                        if (last) Wg[(size_t)n * 65536 + row * 256 + col] = f2b(pv * rtr);
                        else Plds[pa] = f2b(pv);
                    }
        }
        __syncthreads();   // new P fully written before next iteration's g1
    }
}

// ---------------------------------------------------------------------------
// Kernel 5: out = Xn @ W (W symmetric bf16, stride 65536). fp32 out.
// ---------------------------------------------------------------------------
__global__ __launch_bounds__(256) void final_gemm(const u16* __restrict__ xn,
                                                  const u16* __restrict__ Wh,
                                                  float* __restrict__ out) {
    __shared__ u16 sA[128 * 32];
    __shared__ u16 sB[128 * 32];
    const int bid = blockIdx.x;
    const int xcd = bid & 7, slot = bid >> 3;
    const int t = slot & 7;
    const int n = ((slot >> 3) << 3) | xcd;
    const int tr = t >> 1, tc = t & 1;
    const int tid = threadIdx.x;
    const int lane = tid & 63, wave = tid >> 6;
    const int wr = wave >> 1, wc = wave & 1;
    const int l15 = lane & 15, quad = lane >> 4;
    const int row0 = tid >> 2, q = tid & 3;
    const int wb8 = (tid & 192) * 8;

    const u16* gA = xn + (size_t)n * Mm * Dd + (size_t)(tr * 128) * Dd;
    const u16* gB = Wh + (size_t)n * Dd * Dd + (size_t)(tc * 128) * Dd;

    f32x4 acc[4][4];
    #pragma unroll
    for (int i = 0; i < 4; ++i)
        #pragma unroll
        for (int j = 0; j < 4; ++j) acc[i][j] = (f32x4){0.f, 0.f, 0.f, 0.f};

    for (int kk = 0; kk < Dd; kk += 32) {
        glds16(gA + (size_t)row0 * Dd + kk + q * 8, sA + wb8);
        glds16(gA + (size_t)(row0 + 64) * Dd + kk + q * 8, sA + 2048 + wb8);
        glds16(gB + (size_t)row0 * Dd + kk + q * 8, sB + wb8);
        glds16(gB + (size_t)(row0 + 64) * Dd + kk + q * 8, sB + 2048 + wb8);
        __syncthreads();
        bf16x8 a[4], b[4];
        #pragma unroll
        for (int i = 0; i < 4; ++i) a[i] = *(const bf16x8*)(sA + (wr * 64 + i * 16 + l15) * 32 + quad * 8);
        #pragma unroll
        for (int j = 0; j < 4; ++j) b[j] = *(const bf16x8*)(sB + (wc * 64 + j * 16 + l15) * 32 + quad * 8);
        #pragma unroll
        for (int i = 0; i < 4; ++i)
            #pragma unroll
            for (int j = 0; j < 4; ++j)
                acc[i][j] = __builtin_amdgcn_mfma_f32_16x16x32_bf16(a[i], b[j], acc[i][j], 0, 0, 0);
        __syncthreads();
    }

    float* ob = out + (size_t)n * Mm * Dd;
    #pragma unroll
    for (int i = 0; i < 4; ++i)
        #pragma unroll
        for (int j = 0; j < 4; ++j)
            #pragma unroll
            for (int r = 0; r < 4; ++r) {
                int row = tr * 128 + wr * 64 + i * 16 + quad * 4 + r;
                int col = tc * 128 + wc * 64 + j * 16 + l15;
                ob[(size_t)row * Dd + col] = acc[i][j][r];
            }
}

// ---------------------------------------------------------------------------
// Workspace (32MB units):
//  u0-1 xn | u2-3 xnT (dead after sigma) -> W at u2 (32MB)
//  u4-5 sigma fp32 | u6 Sh | u7 Sl | u9 meanPart
// ---------------------------------------------------------------------------
extern "C" void kernel_launch(void* const* d_in, const int* in_sizes, int n_in,
                              void* d_out, int out_size, void* d_ws, size_t ws_size,
                              hipStream_t stream) {
    const float* x = (const float*)d_in[0];
    float* out = (float*)d_out;
    char* ws = (char*)d_ws;
    const size_t MB32 = 33554432;

    u16* xn = (u16*)(ws + 0);
    u16* xnT = (u16*)(ws + 2 * MB32);
    u16* W = (u16*)(ws + 2 * MB32);    // alias xnT (dead after sigma)
    float* sigma = (float*)(ws + 4 * MB32);
    u16* Sh = (u16*)(ws + 6 * MB32);
    u16* Sl = (u16*)(ws + 7 * MB32);
    float* meanPart = (float*)(ws + 9 * MB32);

    mean_part_kernel<<<Nn * 4, 256, 0, stream>>>(x, meanPart);
    center_tr_kernel<<<Nn * 8, 256, 0, stream>>>(x, meanPart, xn, xnT);
    sigma_kernel<<<Nn * 4, 256, 0, stream>>>(xnT, sigma);
    ns_chain_kernel<<<Nn, 1024, 0, stream>>>(sigma, W, Sh, Sl);
    final_gemm<<<Nn * 8, 256, 0, stream>>>(xn, W, out);
}

// Round 6
// 583.286 us; speedup vs baseline: 1.7815x; 1.0744x over previous
//
#include <hip/hip_runtime.h>
#include <stdint.h>

#define Nn 256
#define Mm 512
#define Dd 256

typedef unsigned short u16;
typedef unsigned int u32;
typedef __attribute__((ext_vector_type(8))) short bf16x8;
typedef __attribute__((ext_vector_type(4))) float f32x4;

// manual AGPR stash (gfx950: v_accvgpr_read/write, ISA section 10)
#define AGPR_W(dst, src) asm volatile("v_accvgpr_write_b32 %0, %1" : "=a"(dst) : "v"(src))
#define AGPR_R(dst, src) asm volatile("v_accvgpr_read_b32 %0, %1" : "=v"(dst) : "a"(src))

__device__ __forceinline__ u16 f2b(float f) {
    unsigned u = __float_as_uint(f);
    return (u16)((u + 0x7FFFu + ((u >> 16) & 1u)) >> 16);  // RNE to bf16
}
__device__ __forceinline__ float b2f(u16 h) {
    return __uint_as_float(((unsigned)h) << 16);
}
__device__ __forceinline__ u32 pk2(float lo, float hi) {
    return (u32)f2b(lo) | ((u32)f2b(hi) << 16);
}
__device__ __forceinline__ void glds16(const u16* g, u16* l) {
    __builtin_amdgcn_global_load_lds((const __attribute__((address_space(1))) void*)g,
                                     (__attribute__((address_space(3))) void*)l, 16, 0, 0);
}

// ---------------------------------------------------------------------------
// Kernel 1a: partial column sums. grid = Nn*4; block (n, c) sums 128 rows.
// ---------------------------------------------------------------------------
__global__ __launch_bounds__(256) void mean_part_kernel(const float* __restrict__ x,
                                                        float* __restrict__ meanPart) {
    const int bid = blockIdx.x;
    const int n = bid >> 2, c = bid & 3;
    const int tid = threadIdx.x;
    const float* xb = x + (size_t)n * Mm * Dd + (size_t)c * 128 * Dd;
    float a0 = 0.f, a1 = 0.f, a2 = 0.f, a3 = 0.f;
    for (int m = 0; m < 128; m += 4) {
        a0 += xb[(m + 0) * Dd + tid];
        a1 += xb[(m + 1) * Dd + tid];
        a2 += xb[(m + 2) * Dd + tid];
        a3 += xb[(m + 3) * Dd + tid];
    }
    meanPart[((size_t)n * 4 + c) * Dd + tid] = a0 + a1 + a2 + a3;
}

// ---------------------------------------------------------------------------
// Kernel 1b: center + emit xn bf16 [n][m][d] and xnT bf16 [n][d][m].
// ---------------------------------------------------------------------------
__global__ __launch_bounds__(256) void center_tr_kernel(const float* __restrict__ x,
                                                        const float* __restrict__ meanPart,
                                                        u16* __restrict__ xn,
                                                        u16* __restrict__ xnT) {
    __shared__ float meanS[Dd];
    __shared__ u16 tileS[64 * 66];
    const int bid = blockIdx.x;
    const int n = bid >> 3, mt = bid & 7;
    const int tid = threadIdx.x;

    const float* mp = meanPart + (size_t)n * 4 * Dd;
    meanS[tid] = (mp[tid] + mp[Dd + tid] + mp[2 * Dd + tid] + mp[3 * Dd + tid]) * (1.0f / Mm);
    __syncthreads();

    const float* xb = x + (size_t)n * Mm * Dd;
    u16* xnb = xn + (size_t)n * Mm * Dd;
    u16* xtb = xnT + (size_t)n * Dd * Mm;
    const int mrow = tid >> 4, dq = tid & 15;
    const int tx2 = (tid & 31) * 2, ty = tid >> 5;

    for (int dt = 0; dt < Dd / 64; ++dt) {
        #pragma unroll
        for (int rr = 0; rr < 4; ++rr) {
            int ml = mrow + 16 * rr;
            int m = mt * 64 + ml;
            int d = dt * 64 + dq * 4;
            float4 v = *(const float4*)(xb + (size_t)m * Dd + d);
            float4 mu = *(const float4*)(meanS + d);
            u16 b0 = f2b(v.x - mu.x), b1 = f2b(v.y - mu.y);
            u16 b2 = f2b(v.z - mu.z), b3 = f2b(v.w - mu.w);
            u32 lo = (u32)b0 | ((u32)b1 << 16);
            u32 hi = (u32)b2 | ((u32)b3 << 16);
            *(uint2*)(xnb + (size_t)m * Dd + d) = make_uint2(lo, hi);
            tileS[(dq * 4 + 0) * 66 + ml] = b0;
            tileS[(dq * 4 + 1) * 66 + ml] = b1;
            tileS[(dq * 4 + 2) * 66 + ml] = b2;
            tileS[(dq * 4 + 3) * 66 + ml] = b3;
        }
        __syncthreads();
        #pragma unroll
        for (int r = 0; r < 8; ++r) {
            int dl = r * 8 + ty;
            u32 w = *(const u32*)(tileS + dl * 66 + tx2);
            *(u32*)(xtb + (size_t)(dt * 64 + dl) * Mm + mt * 64 + tx2) = w;
        }
        __syncthreads();
    }
}

// ---------------------------------------------------------------------------
// Kernel 2: sigma[n] = XnT @ XnT^T (raw fp32). XCD-swizzled.
// ---------------------------------------------------------------------------
__global__ __launch_bounds__(256) void sigma_kernel(const u16* __restrict__ xnT,
                                                    float* __restrict__ sigma) {
    __shared__ u16 sA[128 * 32];
    __shared__ u16 sB[128 * 32];
    const int bid = blockIdx.x;
    const int xcd = bid & 7, slot = bid >> 3;
    const int t = slot & 3;
    const int n = ((slot >> 2) << 3) | xcd;
    const int tr = t >> 1, tc = t & 1;
    const int tid = threadIdx.x;
    const int lane = tid & 63, wave = tid >> 6;
    const int wr = wave >> 1, wc = wave & 1;
    const int l15 = lane & 15, quad = lane >> 4;
    const int row0 = tid >> 2, q = tid & 3;
    const int wb8 = (tid & 192) * 8;

    const u16* base = xnT + (size_t)n * Dd * Mm;
    const u16* gA = base + (size_t)(tr * 128) * Mm;
    const u16* gB = base + (size_t)(tc * 128) * Mm;

    f32x4 acc[4][4];
    #pragma unroll
    for (int i = 0; i < 4; ++i)
        #pragma unroll
        for (int j = 0; j < 4; ++j) acc[i][j] = (f32x4){0.f, 0.f, 0.f, 0.f};

    for (int kk = 0; kk < Mm; kk += 32) {
        glds16(gA + (size_t)row0 * Mm + kk + q * 8, sA + wb8);
        glds16(gA + (size_t)(row0 + 64) * Mm + kk + q * 8, sA + 2048 + wb8);
        glds16(gB + (size_t)row0 * Mm + kk + q * 8, sB + wb8);
        glds16(gB + (size_t)(row0 + 64) * Mm + kk + q * 8, sB + 2048 + wb8);
        __syncthreads();
        bf16x8 a[4], b[4];
        #pragma unroll
        for (int i = 0; i < 4; ++i) a[i] = *(const bf16x8*)(sA + (wr * 64 + i * 16 + l15) * 32 + quad * 8);
        #pragma unroll
        for (int j = 0; j < 4; ++j) b[j] = *(const bf16x8*)(sB + (wc * 64 + j * 16 + l15) * 32 + quad * 8);
        #pragma unroll
        for (int i = 0; i < 4; ++i)
            #pragma unroll
            for (int j = 0; j < 4; ++j)
                acc[i][j] = __builtin_amdgcn_mfma_f32_16x16x32_bf16(a[i], b[j], acc[i][j], 0, 0, 0);
        __syncthreads();
    }

    float* sg = sigma + (size_t)n * Dd * Dd;
    #pragma unroll
    for (int i = 0; i < 4; ++i)
        #pragma unroll
        for (int j = 0; j < 4; ++j)
            #pragma unroll
            for (int r = 0; r < 4; ++r) {
                int row = tr * 128 + wr * 64 + i * 16 + quad * 4 + r;
                int col = tc * 128 + wc * 64 + j * 16 + l15;
                sg[row * Dd + col] = acc[i][j][r];
            }
}

// ---------------------------------------------------------------------------
// Fused NS chain v6: one block (1024 thr, 16 waves) per batch.
// Dataflow identical to v5 (bitwise-same accumulation order), but g1 is
// FUSED into g2's column passes so the 32-reg qbf array disappears:
//   per jp (4 passes):
//     g1-panel: all 16 waves compute Q[:, jp*64..+64] (16x64 strip each,
//               acc1 = 16 f32) and dump straight to sQ strip (uint2)
//     g2: P3 panel = P @ Qpanel (acc2 = 16 f32) -> AGPR stash p3a
//   g3: P' = 1.5P - 0.5*P3@(Sh+Sl), S stream prefetch distance 2.
//   Last iter writes f2b(pv*rtr) into Plds; W streamed out coalesced.
// ---------------------------------------------------------------------------
__device__ __forceinline__ bf16x8 ldP(const u16* Plds, int row, int ch) {
    return *(const bf16x8*)(Plds + row * 256 + ((ch ^ (row & 7)) << 3));
}

__global__ __launch_bounds__(1024, 4) void ns_chain_kernel(const float* __restrict__ sigma,
                                                           u16* __restrict__ Wg,
                                                           u16* __restrict__ Sh,
                                                           u16* __restrict__ Sl) {
    __shared__ __align__(16) u16 lds[81920];   // 160 KB
    u16* Plds = lds;
    u16* strips = lds + 65536;   // 16384 u16 = 32KB
    u16* sQ = strips;            // g1g2: [64][256]
    u16* sA = strips;            // g3: [256][32]
    u16* sS = strips + 8192;     // g3: Sh [128][32] + Sl [128][32]

    const int n = blockIdx.x, tid = threadIdx.x;
    const int lane = tid & 63, wave = tid >> 6;
    const int l15 = lane & 15, quad = lane >> 4;
    const int wr8 = wave >> 1, wc2 = wave & 1;    // g3: 8x2 grid of 32x64

    const float* sg = sigma + (size_t)n * 65536;
    u16* shp = Sh + (size_t)n * 65536;
    u16* slp = Sl + (size_t)n * 65536;

    // ---- phase 0: trace, split S -> global, P1 -> LDS (swizzled) ----
    float* red = (float*)strips;
    if (tid < 256) red[tid] = sg[tid * 257];
    __syncthreads();
    for (int s = 128; s > 0; s >>= 1) {
        if (tid < s) red[tid] += red[tid + s];
        __syncthreads();
    }
    const float inv = 1.0f / red[0];
    const float rtr = sqrtf(511.0f * inv);

    #pragma unroll 4
    for (int itp = 0; itp < 16; ++itp) {
        int idx = itp * 4096 + tid * 4;
        float4 v = *(const float4*)(sg + idx);
        int row = idx >> 8, col = idx & 255;
        float s0 = v.x * inv, s1 = v.y * inv, s2 = v.z * inv, s3 = v.w * inv;
        u16 h0 = f2b(s0), h1 = f2b(s1), h2 = f2b(s2), h3 = f2b(s3);
        *(uint2*)(shp + idx) = make_uint2((u32)h0 | ((u32)h1 << 16), (u32)h2 | ((u32)h3 << 16));
        u16 e0 = f2b(s0 - b2f(h0)), e1 = f2b(s1 - b2f(h1));
        u16 e2 = f2b(s2 - b2f(h2)), e3 = f2b(s3 - b2f(h3));
        *(uint2*)(slp + idx) = make_uint2((u32)e0 | ((u32)e1 << 16), (u32)e2 | ((u32)e3 << 16));
        u16 p0 = f2b(((row == col + 0) ? 1.5f : 0.f) - 0.5f * s0);
        u16 p1 = f2b(((row == col + 1) ? 1.5f : 0.f) - 0.5f * s1);
        u16 p2 = f2b(((row == col + 2) ? 1.5f : 0.f) - 0.5f * s2);
        u16 p3 = f2b(((row == col + 3) ? 1.5f : 0.f) - 0.5f * s3);
        int pa = row * 256 + (((col >> 3) ^ (row & 7)) << 3) + (col & 7);
        *(uint2*)(Plds + pa) = make_uint2((u32)p0 | ((u32)p1 << 16), (u32)p2 | ((u32)p3 << 16));
    }
    __syncthreads();   // full drain: S stores visible before any re-read

    // S-staging per-lane constants: waves 0-7 stage Sh, 8-15 stage Sl.
    const u16* sBase = (wave < 8) ? shp : slp;
    const int w8 = wave & 7;
    const int cl_st = w8 * 16 + (lane >> 2);        // strip row (= S column)
    const int gch_st = (lane & 3) ^ (cl_st & 3);    // pre-swizzled src chunk
    u16* sDst = sS + ((wave < 8) ? 0 : 4096) + w8 * 512 + lane * 8;

    // ---- 3 NS iterations ----
    #pragma unroll 1
    for (int it = 0; it < 3; ++it) {
        const bool last = (it == 2);
        u32 p3a[32];    // AGPR-stashed via v_accvgpr_* (written g2, read g3)

        // ---- g1+g2 fused: per column panel jp ----
        #pragma unroll
        for (int jp = 0; jp < 4; ++jp) {
            // g1-panel: Q[:, jp*64..+64]; this wave computes rows wave*16..+16
            {
                f32x4 acc1[4];
                #pragma unroll
                for (int jj = 0; jj < 4; ++jj) acc1[jj] = (f32x4){0.f, 0.f, 0.f, 0.f};
                #pragma unroll
                for (int s = 0; s < 8; ++s) {
                    bf16x8 a = ldP(Plds, wave * 16 + l15, s * 4 + quad);
                    #pragma unroll
                    for (int jj = 0; jj < 4; ++jj) {
                        bf16x8 b = ldP(Plds, jp * 64 + jj * 16 + l15, s * 4 + quad);
                        acc1[jj] = __builtin_amdgcn_mfma_f32_16x16x32_bf16(a, b, acc1[jj], 0, 0, 0);
                    }
                }
                // dump panel: sQ[cl][k] = Q[k][jp*64+cl], k band = wave*16..+16
                #pragma unroll
                for (int jj = 0; jj < 4; ++jj) {
                    int cl = jj * 16 + l15;
                    int k0 = wave * 16 + quad * 4;
                    int addr = cl * 256 + (((k0 >> 3) ^ (cl & 7)) << 3) + (k0 & 7);
                    *(uint2*)(sQ + addr) = make_uint2(pk2(acc1[jj][0], acc1[jj][1]),
                                                      pk2(acc1[jj][2], acc1[jj][3]));
                }
            }
            __syncthreads();
            // g2: P3 panel cols jp*64..+64, this wave rows wave*16..+16
            {
                f32x4 acc2[4];
                #pragma unroll
                for (int jj = 0; jj < 4; ++jj) acc2[jj] = (f32x4){0.f, 0.f, 0.f, 0.f};
                #pragma unroll
                for (int s = 0; s < 8; ++s) {
                    bf16x8 a = ldP(Plds, wave * 16 + l15, s * 4 + quad);
                    #pragma unroll
                    for (int jj = 0; jj < 4; ++jj) {
                        int cl = jj * 16 + l15;
                        bf16x8 b = *(const bf16x8*)(sQ + cl * 256 + (((s * 4 + quad) ^ (cl & 7)) << 3));
                        acc2[jj] = __builtin_amdgcn_mfma_f32_16x16x32_bf16(a, b, acc2[jj], 0, 0, 0);
                    }
                }
                #pragma unroll
                for (int jj = 0; jj < 4; ++jj)
                    #pragma unroll
                    for (int rh = 0; rh < 2; ++rh)
                        AGPR_W(p3a[(jp * 4 + jj) * 2 + rh], pk2(acc2[jj][2 * rh], acc2[jj][2 * rh + 1]));
            }
            __syncthreads();
        }

        // ---- g3: P' = 1.5P - 0.5*P3@(Sh+Sl), 2 col passes, 32x64 tiles ----
        // S stream prefetch distance 2 (gregA even steps, gregB odd steps).
        uint4 gregA = *(const uint4*)(sBase + (size_t)cl_st * 256 + gch_st * 8);          // t=0
        uint4 gregB = *(const uint4*)(sBase + (size_t)cl_st * 256 + 32 + gch_st * 8);     // t=1
        #pragma unroll 1
        for (int jc = 0; jc < 2; ++jc) {
            f32x4 acc3[2][4];
            #pragma unroll
            for (int i16 = 0; i16 < 2; ++i16)
                #pragma unroll
                for (int j = 0; j < 4; ++j) acc3[i16][j] = (f32x4){0.f, 0.f, 0.f, 0.f};
            #pragma unroll
            for (int s = 0; s < 8; ++s) {
                // dump A-panel (k = cols s*32..+32 of P3) from AGPR stash
                #pragma unroll
                for (int jjh = 0; jjh < 2; ++jjh) {
                    int jjsrc = (s & 1) * 2 + jjh;
                    int kloc = jjh * 16 + l15;
                    int ch = kloc >> 3, k7 = kloc & 7;
                    #pragma unroll
                    for (int rh = 0; rh < 2; ++rh) {
                        u32 wv;
                        AGPR_R(wv, p3a[((s >> 1) * 4 + jjsrc) * 2 + rh]);
                        #pragma unroll
                        for (int bit = 0; bit < 2; ++bit) {
                            int row = wave * 16 + quad * 4 + 2 * rh + bit;
                            int sw = (row ^ (row >> 2)) & 3;
                            sA[row * 32 + ((ch ^ sw) << 3) + k7] =
                                (u16)(bit ? (wv >> 16) : (wv & 0xffffu));
                        }
                    }
                }
                // S panel for THIS step (loaded 2 steps ago) + prefetch t+2
                if ((s & 1) == 0) {
                    *(uint4*)sDst = gregA;
                    int t2 = jc * 8 + s + 2;
                    if (t2 < 16) {
                        int jcn = t2 >> 3, sn = t2 & 7;
                        gregA = *(const uint4*)(sBase + (size_t)(jcn * 128 + cl_st) * 256 + sn * 32 + gch_st * 8);
                    }
                } else {
                    *(uint4*)sDst = gregB;
                    int t2 = jc * 8 + s + 2;
                    if (t2 < 16) {
                        int jcn = t2 >> 3, sn = t2 & 7;
                        gregB = *(const uint4*)(sBase + (size_t)(jcn * 128 + cl_st) * 256 + sn * 32 + gch_st * 8);
                    }
                }
                asm volatile("s_waitcnt lgkmcnt(0)" ::: "memory");
                __builtin_amdgcn_s_barrier();
                // compute: 32x64 tile per wave (rows wr8*32.., cols jc*128+wc2*64..)
                {
                    bf16x8 a[2];
                    #pragma unroll
                    for (int i16 = 0; i16 < 2; ++i16) {
                        int ar = wr8 * 32 + i16 * 16 + l15;
                        int asw = (ar ^ (ar >> 2)) & 3;
                        a[i16] = *(const bf16x8*)(sA + ar * 32 + ((quad ^ asw) << 3));
                    }
                    #pragma unroll
                    for (int j = 0; j < 4; ++j) {
                        int cl = wc2 * 64 + j * 16 + l15;
                        int co = cl * 32 + ((quad ^ (cl & 3)) << 3);
                        bf16x8 bh = *(const bf16x8*)(sS + co);
                        bf16x8 bl = *(const bf16x8*)(sS + 4096 + co);
                        #pragma unroll
                        for (int i16 = 0; i16 < 2; ++i16)
                            acc3[i16][j] = __builtin_amdgcn_mfma_f32_16x16x32_bf16(a[i16], bh, acc3[i16][j], 0, 0, 0);
                        #pragma unroll
                        for (int i16 = 0; i16 < 2; ++i16)
                            acc3[i16][j] = __builtin_amdgcn_mfma_f32_16x16x32_bf16(a[i16], bl, acc3[i16][j], 0, 0, 0);
                    }
                }
                asm volatile("s_waitcnt lgkmcnt(0)" ::: "memory");
                __builtin_amdgcn_s_barrier();
            }
            // epilogue for this column pass (own cells only -> race-free)
            #pragma unroll
            for (int i16 = 0; i16 < 2; ++i16)
                #pragma unroll
                for (int j = 0; j < 4; ++j)
                    #pragma unroll
                    for (int r = 0; r < 4; ++r) {
                        int row = wr8 * 32 + i16 * 16 + quad * 4 + r;
                        int col = jc * 128 + wc2 * 64 + j * 16 + l15;
                        int pa = row * 256 + (((col >> 3) ^ (row & 7)) << 3) + (col & 7);
                        float pv = 1.5f * b2f(Plds[pa]) - 0.5f * acc3[i16][j][r];
                        Plds[pa] = f2b(last ? pv * rtr : pv);
                    }
        }
        __syncthreads();   // new P (or W) fully written before next phase
    }

    // ---- stream W = Plds out, coalesced uint4 ----
    u16* wg = Wg + (size_t)n * 65536;
    #pragma unroll
    for (int q = 0; q < 8; ++q) {
        int f = q * 1024 + tid;       // 8192 chunks of 8 u16
        int row = f >> 5, ch = f & 31;
        uint4 v = *(const uint4*)(Plds + row * 256 + ((ch ^ (row & 7)) << 3));
        *(uint4*)(wg + row * 256 + ch * 8) = v;
    }
}

// ---------------------------------------------------------------------------
// Kernel 5: out = Xn @ W (W symmetric bf16, stride 65536). fp32 out.
// ---------------------------------------------------------------------------
__global__ __launch_bounds__(256) void final_gemm(const u16* __restrict__ xn,
                                                  const u16* __restrict__ Wh,
                                                  float* __restrict__ out) {
    __shared__ u16 sA[128 * 32];
    __shared__ u16 sB[128 * 32];
    const int bid = blockIdx.x;
    const int xcd = bid & 7, slot = bid >> 3;
    const int t = slot & 7;
    const int n = ((slot >> 3) << 3) | xcd;
    const int tr = t >> 1, tc = t & 1;
    const int tid = threadIdx.x;
    const int lane = tid & 63, wave = tid >> 6;
    const int wr = wave >> 1, wc = wave & 1;
    const int l15 = lane & 15, quad = lane >> 4;
    const int row0 = tid >> 2, q = tid & 3;
    const int wb8 = (tid & 192) * 8;

    const u16* gA = xn + (size_t)n * Mm * Dd + (size_t)(tr * 128) * Dd;
    const u16* gB = Wh + (size_t)n * Dd * Dd + (size_t)(tc * 128) * Dd;

    f32x4 acc[4][4];
    #pragma unroll
    for (int i = 0; i < 4; ++i)
        #pragma unroll
        for (int j = 0; j < 4; ++j) acc[i][j] = (f32x4){0.f, 0.f, 0.f, 0.f};

    for (int kk = 0; kk < Dd; kk += 32) {
        glds16(gA + (size_t)row0 * Dd + kk + q * 8, sA + wb8);
        glds16(gA + (size_t)(row0 + 64) * Dd + kk + q * 8, sA + 2048 + wb8);
        glds16(gB + (size_t)row0 * Dd + kk + q * 8, sB + wb8);
        glds16(gB + (size_t)(row0 + 64) * Dd + kk + q * 8, sB + 2048 + wb8);
        __syncthreads();
        bf16x8 a[4], b[4];
        #pragma unroll
        for (int i = 0; i < 4; ++i) a[i] = *(const bf16x8*)(sA + (wr * 64 + i * 16 + l15) * 32 + quad * 8);
        #pragma unroll
        for (int j = 0; j < 4; ++j) b[j] = *(const bf16x8*)(sB + (wc * 64 + j * 16 + l15) * 32 + quad * 8);
        #pragma unroll
        for (int i = 0; i < 4; ++i)
            #pragma unroll
            for (int j = 0; j < 4; ++j)
                acc[i][j] = __builtin_amdgcn_mfma_f32_16x16x32_bf16(a[i], b[j], acc[i][j], 0, 0, 0);
        __syncthreads();
    }

    float* ob = out + (size_t)n * Mm * Dd;
    #pragma unroll
    for (int i = 0; i < 4; ++i)
        #pragma unroll
        for (int j = 0; j < 4; ++j)
            #pragma unroll
            for (int r = 0; r < 4; ++r) {
                int row = tr * 128 + wr * 64 + i * 16 + quad * 4 + r;
                int col = tc * 128 + wc * 64 + j * 16 + l15;
                ob[(size_t)row * Dd + col] = acc[i][j][r];
            }
}

// ---------------------------------------------------------------------------
// Workspace (32MB units):
//  u0-1 xn | u2-3 xnT (dead after sigma) -> W at u2 (32MB)
//  u4-5 sigma fp32 | u6 Sh | u7 Sl | u9 meanPart
// ---------------------------------------------------------------------------
extern "C" void kernel_launch(void* const* d_in, const int* in_sizes, int n_in,
                              void* d_out, int out_size, void* d_ws, size_t ws_size,
                              hipStream_t stream) {
    const float* x = (const float*)d_in[0];
    float* out = (float*)d_out;
    char* ws = (char*)d_ws;
    const size_t MB32 = 33554432;

    u16* xn = (u16*)(ws + 0);
    u16* xnT = (u16*)(ws + 2 * MB32);
    u16* W = (u16*)(ws + 2 * MB32);    // alias xnT (dead after sigma)
    float* sigma = (float*)(ws + 4 * MB32);
    u16* Sh = (u16*)(ws + 6 * MB32);
    u16* Sl = (u16*)(ws + 7 * MB32);
    float* meanPart = (float*)(ws + 9 * MB32);

    mean_part_kernel<<<Nn * 4, 256, 0, stream>>>(x, meanPart);
    center_tr_kernel<<<Nn * 8, 256, 0, stream>>>(x, meanPart, xn, xnT);
    sigma_kernel<<<Nn * 4, 256, 0, stream>>>(xnT, sigma);
    ns_chain_kernel<<<Nn, 1024, 0, stream>>>(sigma, W, Sh, Sl);
    final_gemm<<<Nn * 8, 256, 0, stream>>>(xn, W, out);
}